// Round 7
// baseline (2469.074 us; speedup 1.0000x reference)
//
#include <hip/hip_runtime.h>

#define NN 16384
#define PERG 512
#define NGR 32
#define NE 262144
#define GSEG 9216            // per-graph edge segment capacity (max count ~8.6k)

// ---------- helpers ----------
__device__ __forceinline__ unsigned encf(float f){
  unsigned u = __float_as_uint(f);
  return (u & 0x80000000u) ? ~u : (u | 0x80000000u);
}
__device__ __forceinline__ float decf(unsigned e){
  unsigned u = (e & 0x80000000u) ? (e ^ 0x80000000u) : ~e;
  return __uint_as_float(u);
}

// ---------- one-time: pad copies for K%16==0 GEMMs ----------
__global__ void k_padx(const float* __restrict__ x, float* __restrict__ xp){
  int i = blockIdx.x*256 + threadIdx.x;          // over NN*112
  if (i < NN*112){ int r = i/112, c = i-r*112; xp[i] = (c<107) ? x[r*107+c] : 0.f; }
}
__global__ void k_padw(const float* __restrict__ Wsrc, float* __restrict__ Wdst,
                       int Ksrc, int Kdst, int N){
  int i = blockIdx.x*256 + threadIdx.x;
  if (i < Kdst*N){ int r = i/N, c = i-r*N; Wdst[i] = (r<Ksrc) ? Wsrc[r*N+c] : 0.f; }
}

// ---------- one-time bucketing: edges -> graph-major segments ----------
__global__ __launch_bounds__(256) void k_bucket(const int* __restrict__ ei, int* __restrict__ gcount,
    int* __restrict__ bsrc, int* __restrict__ bdst, int* __restrict__ bem, int* __restrict__ beid){
  __shared__ int cnt[NGR];
  __shared__ int base[NGR];
  int t = threadIdx.x;
  if (t < NGR) cnt[t] = 0;
  __syncthreads();
  int e = blockIdx.x*256 + t;
  int s=0,d=0,g=0,r=0;
  bool ok = (e < NE);
  if (ok){ s = ei[e]; d = ei[NE+e]; g = s >> 9; r = atomicAdd(&cnt[g],1); }
  __syncthreads();
  if (t < NGR) base[t] = atomicAdd(&gcount[t], cnt[t]);
  __syncthreads();
  if (ok){
    int pos = g*GSEG + base[g] + r;
    bsrc[pos]=s; bdst[pos]=d; bem[pos]=1; beid[pos]=e;
  }
}
__global__ void k_init_nodes(int* __restrict__ valid){
  int i = blockIdx.x*256 + threadIdx.x;
  if (i < NN) valid[i]=1;
}

// ---------- dense matmul C[M,N] = A[M,KP] @ W[KP,N], f32, KP%16==0 ----------
__global__ __launch_bounds__(256) void k_mm(const float* __restrict__ A, const float* __restrict__ W,
                                            float* __restrict__ C, int KP, int N){
  __shared__ float As[16][132];   // A transposed: As[k][row]
  __shared__ float Ws[16][68];
  int col0 = blockIdx.x*64, row0 = blockIdx.y*128;
  int t = threadIdx.x;
  int tx = t & 15, ty = t >> 4;
  int ar = t >> 1;
  int ak = (t & 1) * 8;
  int wk = t >> 4;
  int wn = (t & 15) * 4;
  int wc = col0 + wn;

  float acc[8][4];
#pragma unroll
  for (int i=0;i<8;i++)
#pragma unroll
    for (int j=0;j<4;j++) acc[i][j]=0.f;

  const float* Arow = A + (size_t)(row0+ar)*KP;

  for (int k0=0; k0<KP; k0+=16){
    float4 a0 = *(const float4*)&Arow[k0 + ak];
    float4 a1 = *(const float4*)&Arow[k0 + ak + 4];
    float4 w0;
    const float* wp = &W[(size_t)(k0+wk)*N + wc];
    if (wc+3 < N) w0 = *(const float4*)wp;
    else { w0.x=(wc<N)?wp[0]:0.f; w0.y=(wc+1<N)?wp[1]:0.f; w0.z=(wc+2<N)?wp[2]:0.f; w0.w=0.f; }
    __syncthreads();
    As[ak+0][ar]=a0.x; As[ak+1][ar]=a0.y; As[ak+2][ar]=a0.z; As[ak+3][ar]=a0.w;
    As[ak+4][ar]=a1.x; As[ak+5][ar]=a1.y; As[ak+6][ar]=a1.z; As[ak+7][ar]=a1.w;
    *(float4*)&Ws[wk][wn] = w0;
    __syncthreads();
#pragma unroll
    for (int kk=0;kk<16;kk++){
      float4 A0 = *(const float4*)&As[kk][ty*8];
      float4 A1 = *(const float4*)&As[kk][ty*8+4];
      float4 B0 = *(const float4*)&Ws[kk][tx*4];
      float a[8] = {A0.x,A0.y,A0.z,A0.w,A1.x,A1.y,A1.z,A1.w};
      float b[4] = {B0.x,B0.y,B0.z,B0.w};
#pragma unroll
      for (int i=0;i<8;i++)
#pragma unroll
        for (int j=0;j<4;j++) acc[i][j] += a[i]*b[j];
    }
  }

#pragma unroll
  for (int i=0;i<8;i++){
    int r = row0 + ty*8 + i;
    int cc = col0 + tx*4;
    if (cc+3 < N){
      float4 v = {acc[i][0],acc[i][1],acc[i][2],acc[i][3]};
      *(float4*)&C[(size_t)r*N+cc] = v;
    } else {
#pragma unroll
      for (int j=0;j<4;j++) if (cc+j<N) C[(size_t)r*N+cc+j] = acc[i][j];
    }
  }
}

// ---------- per-graph CSR (by dst) + node incidence lists + node prep ----------
__global__ __launch_bounds__(1024) void k_prep(const int* __restrict__ bsrc, const int* __restrict__ bdst,
    const int* __restrict__ bem, const int* __restrict__ gcount,
    int* __restrict__ row_s, int* __restrict__ row_e, int* __restrict__ elist,
    int* __restrict__ inc, int* __restrict__ inc_rs, int* __restrict__ inc_re,
    float* __restrict__ dinv, float* __restrict__ selfco){
  int g = blockIdx.x, t = threadIdx.x;
  __shared__ int cnt_l[PERG];
  __shared__ int cnt2[PERG];
  __shared__ int scn[PERG];
  __shared__ int cur[PERG];
  __shared__ int cur2[PERG];
  __shared__ unsigned char hs_l[PERG];
  if (t<PERG){ cnt_l[t]=0; cnt2[t]=0; hs_l[t]=0; }
  __syncthreads();
  int nE = min(gcount[g], GSEG); int base = g*GSEG; int base2 = g*2*GSEG;
  for (int k=t;k<nE;k+=1024){
    if (bem[base+k]){
      int d = bdst[base+k]&511, s = bsrc[base+k]&511;
      atomicAdd(&cnt_l[d],1);
      if (s==d) hs_l[d]=1;
      atomicAdd(&cnt2[d],1);
      atomicAdd(&cnt2[s],1);
    }
  }
  __syncthreads();
  // scan 1: dst-CSR
  if (t<PERG) scn[t]=cnt_l[t];
  __syncthreads();
  for (int off=1; off<PERG; off<<=1){
    int v = (t<PERG && t>=off) ? scn[t-off] : 0;
    __syncthreads();
    if (t<PERG) scn[t]+=v;
    __syncthreads();
  }
  if (t<PERG){
    int excl = scn[t]-cnt_l[t];
    row_s[g*PERG+t] = base+excl;
    row_e[g*PERG+t] = base+scn[t];
    cur[t] = excl;
    float deg = (float)cnt_l[t] + (hs_l[t]?0.f:1.f);
    dinv[g*PERG+t]   = rsqrtf(deg);
    selfco[g*PERG+t] = hs_l[t]?0.f:(1.f/deg);
  }
  __syncthreads();
  // scan 2: incidence offsets
  if (t<PERG) scn[t]=cnt2[t];
  __syncthreads();
  for (int off=1; off<PERG; off<<=1){
    int v = (t<PERG && t>=off) ? scn[t-off] : 0;
    __syncthreads();
    if (t<PERG) scn[t]+=v;
    __syncthreads();
  }
  if (t<PERG){
    int excl = scn[t]-cnt2[t];
    inc_rs[g*PERG+t] = base2+excl;
    inc_re[g*PERG+t] = base2+scn[t];
    cur2[t] = excl;
  }
  __syncthreads();
  for (int k=t;k<nE;k+=1024){
    if (bem[base+k]){
      int d = bdst[base+k]&511, s = bsrc[base+k]&511;
      elist[base + atomicAdd(&cur[d],1)] = base+k;
      inc[base2 + atomicAdd(&cur2[d],1)] = (s<<14)|k;
      inc[base2 + atomicAdd(&cur2[s],1)] = (d<<14)|k;
    }
  }
}

// ---------- GCN agg + bias + pool-score partials (fused; XCD-swizzled) ----------
template<int FO>
__global__ __launch_bounds__(256) void k_aggab(const float* __restrict__ h, const int* __restrict__ row_s,
    const int* __restrict__ row_e, const int* __restrict__ elist, const int* __restrict__ bsrc,
    const float* __restrict__ dinv, const float* __restrict__ selfco, const float* __restrict__ bias,
    const float* __restrict__ Pw, float* __restrict__ y, float* __restrict__ aval, float* __restrict__ bval){
  constexpr int Q = (FO+63)/64;
  int lane = threadIdx.x & 63;
  int nblk = (blockIdx.x & 7)*512 + (blockIdx.x >> 3);
  int i = nblk*4 + (threadIdx.x>>6);
  float acc[Q];
#pragma unroll
  for (int q=0;q<Q;q++) acc[q]=0.f;
  int s0 = row_s[i], s1 = row_e[i];
  float di = dinv[i];
  for (int p=s0; p<s1; p++){
    int e = elist[p]; int s = bsrc[e];
    float nr = di * dinv[s];
    const float* hrow = h + (size_t)s*FO;
#pragma unroll
    for (int q=0;q<Q;q++){ int c=lane+q*64; if (c<FO) acc[q] += nr*hrow[c]; }
  }
  float sc = selfco[i];
  const float* hi = h + (size_t)i*FO;
  float* yi = y + (size_t)i*FO;
  float sa=0.f, sb=0.f;
#pragma unroll
  for (int q=0;q<Q;q++){
    int c = lane+q*64;
    if (c<FO){
      float v = acc[q] + sc*hi[c] + bias[c];
      yi[c] = v;
      sa += v*Pw[c];
      sb += v*Pw[FO+c];
    }
  }
  for (int o=32;o;o>>=1){ sa += __shfl_xor(sa,o); sb += __shfl_xor(sb,o); }
  if (lane==0){ aval[i]=sa; bval[i]=sb; }
}

// ---------- pool: softmax + node-centric greedy match + remap + dedupe ----------
#define NEPT 9   // 9 * 1024 = 9216 = GSEG
__global__ __launch_bounds__(1024) void k_pool(const int* __restrict__ gcount,
    int* __restrict__ bsrc, int* __restrict__ bdst, int* __restrict__ bem, const int* __restrict__ beid,
    const int* __restrict__ inc, const int* __restrict__ inc_rs, const int* __restrict__ inc_re,
    const float* __restrict__ aval, const float* __restrict__ bval, const float* __restrict__ Pb,
    float* __restrict__ nscore, int* __restrict__ partner, int* __restrict__ valid, int* __restrict__ table){
  int g = blockIdx.x, t = threadIdx.x;
  __shared__ unsigned sbl[GSEG];          // 36.9 KB: per-edge score bits
  __shared__ unsigned mx[PERG];
  __shared__ float den[PERG];
  __shared__ unsigned char marked[PERG];
  __shared__ unsigned short clus[PERG];
  __shared__ unsigned short best_e[PERG];
  __shared__ unsigned short best_o[PERG];
  __shared__ int flag;
  int nE = min(gcount[g], GSEG), base = g*GSEG;
  if (t<PERG){
    mx[t]=0u; den[t]=0.f;
    marked[t] = valid[(g<<9)+t] ? 0 : 1;
    clus[t] = (unsigned short)t;
    nscore[(g<<9)+t] = 1.f;
    partner[(g<<9)+t] = -1;
  }
  __syncthreads();

  // ---- softmax over edges grouped by dst (scores -> sbl) ----
  int sL[NEPT], dL[NEPT];
  float rawv[NEPT];
  unsigned em = 0u;
#pragma unroll
  for (int j=0;j<NEPT;j++){
    sL[j]=0; dL[j]=0; rawv[j]=0.f;
    int k = t + j*1024;
    if (k < nE && bem[base+k]){
      sL[j] = bsrc[base+k]&511; dL[j] = bdst[base+k]&511;
      rawv[j] = aval[(g<<9)+sL[j]] + bval[(g<<9)+dL[j]] + Pb[0];
      em |= (1u<<j);
      atomicMax(&mx[dL[j]], encf(rawv[j]));
    }
  }
  __syncthreads();
  float exv[NEPT];
#pragma unroll
  for (int j=0;j<NEPT;j++){
    exv[j]=0.f;
    if (em & (1u<<j)){
      exv[j] = expf(rawv[j] - decf(mx[dL[j]]));
      atomicAdd(&den[dL[j]], exv[j]);
    }
  }
  __syncthreads();
#pragma unroll
  for (int j=0;j<NEPT;j++){
    if (em & (1u<<j)){
      int k = t + j*1024;
      float sc = exv[j]/fmaxf(den[dL[j]],1e-16f) + 0.1f;
      sbl[k] = __float_as_uint(sc);
    }
  }
  __syncthreads();

  // ---- greedy matching: per-node scan (no atomics) ----
  for (int round=0; round<600; ++round){
    if (t<PERG){ best_e[t]=0xFFFF; best_o[t]=0xFFFF; }
    if (t==0) flag = 0;
    __syncthreads();
    if (t<PERG && !marked[t]){
      int n = t;
      unsigned bsb = 0u; int bk = -1, bo = 0; unsigned bbe = 0xFFFFFFFFu;
      int j1 = inc_re[(g<<9)+n];
      for (int j=inc_rs[(g<<9)+n]; j<j1; j++){
        unsigned en = (unsigned)inc[j];
        int o = en>>14, k_ = en & 0x3FFF;
        if (marked[o]) continue;
        unsigned sv = sbl[k_];
        if (sv < bsb) continue;
        if (sv > bsb){ bsb=sv; bk=k_; bo=o; bbe=0xFFFFFFFFu; }
        else {
          if (bbe==0xFFFFFFFFu) bbe = (unsigned)beid[base+bk];
          unsigned nb = (unsigned)beid[base+k_];
          if (nb < bbe){ bk=k_; bo=o; bbe=nb; }
        }
      }
      if (bk>=0){ best_e[n]=(unsigned short)bk; best_o[n]=(unsigned short)bo; flag=1; }
    }
    __syncthreads();
    if (!flag) break;
    if (t<PERG && !marked[t]){
      int n = t;
      int bk = best_e[n];
      if (bk != 0xFFFF){
        int o = best_o[n];
        if (o == n){                      // self-loop: mark node, score it
          nscore[(g<<9)+n] = __uint_as_float(sbl[bk]);
          marked[n] = 1;
        } else if (best_e[o]==bk && n<o){ // mutual max: contract o into n
          clus[o] = (unsigned short)n;
          nscore[(g<<9)+n] = __uint_as_float(sbl[bk]);
          valid[(g<<9)+o] = 0;
          partner[(g<<9)+n] = (g<<9)+o;
          marked[n] = 1; marked[o] = 1;
        }
      }
    }
    __syncthreads();
  }
  __syncthreads();

  // ---- remap + dedupe (graph-local key table in global scratch) ----
#pragma unroll
  for (int j=0;j<NEPT;j++){
    if (em & (1u<<j)){
      int k = t + j*1024;
      int ns = clus[sL[j]], nd = clus[dL[j]];
      sL[j]=ns; dL[j]=nd;
      bsrc[base+k] = (g<<9)+ns; bdst[base+k] = (g<<9)+nd;
      table[(g<<18) | (ns<<9) | nd] = 0x7FFFFFFF;
    }
  }
  __syncthreads();
#pragma unroll
  for (int j=0;j<NEPT;j++){
    if (em & (1u<<j)){
      int k = t + j*1024;
      atomicMin(&table[(g<<18) | (sL[j]<<9) | dL[j]], base+k);
    }
  }
  __syncthreads();
#pragma unroll
  for (int j=0;j<NEPT;j++){
    if (em & (1u<<j)){
      int k = t + j*1024;
      if (table[(g<<18) | (sL[j]<<9) | dL[j]] != base+k) bem[base+k] = 0;
    }
  }
}

// ---------- pool: new_x = relu((y[i]+y[partner]) * score * valid), pad-zeroed ----------
template<int FO, int FOP>
__global__ __launch_bounds__(256) void k_newx(const float* __restrict__ y, const int* __restrict__ partner,
    const float* __restrict__ nscore, const int* __restrict__ valid, float* __restrict__ out){
  constexpr int Q = (FOP+63)/64;
  int lane = threadIdx.x & 63;
  int nblk = (blockIdx.x & 7)*512 + (blockIdx.x >> 3);
  int i = nblk*4 + (threadIdx.x>>6);
  int v = valid[i];
  float ns = nscore[i];
  int p = partner[i];
  const float* yi = y + (size_t)i*FO;
  const float* yp = (p>=0) ? (y + (size_t)p*FO) : yi;
  float* oi = out + (size_t)i*FOP;
#pragma unroll
  for (int q=0;q<Q;q++){
    int c = lane + q*64;
    if (c<FO){
      float val = yi[c];
      if (p>=0) val += yp[c];
      val *= ns;
      oi[c] = v ? fmaxf(val,0.f) : 0.f;
    } else if (c<FOP){
      oi[c] = 0.f;
    }
  }
}

// ---------- readout: stage 1, per-(graph, 64-row part) partial max ----------
__global__ __launch_bounds__(256) void k_gmax(const float* __restrict__ x, const int* __restrict__ valid,
                                              float* __restrict__ part){
  int g = blockIdx.x >> 3, rp = blockIdx.x & 7;
  __shared__ int lv[64];
  int r0 = rp*64;
  if (threadIdx.x < 64) lv[threadIdx.x] = valid[g*PERG + r0 + threadIdx.x];
  __syncthreads();
  const float* base = x + ((size_t)g*PERG + r0)*600;
  for (int c=threadIdx.x; c<600; c+=256){
    float m = -1e30f;
    for (int r=0;r<64;r++)
      if (lv[r]) m = fmaxf(m, base[(size_t)r*600+c]);
    part[(size_t)(g*8+rp)*600 + c] = m;
  }
}
__global__ __launch_bounds__(256) void k_head(const float* __restrict__ part,
    const float* __restrict__ L1w, const float* __restrict__ L1b,
    const float* __restrict__ L2w, const float* __restrict__ L2b,
    const float* __restrict__ L3w, const float* __restrict__ L3b, float* __restrict__ out){
  int g = blockIdx.x, t = threadIdx.x;
  __shared__ float gg[600];
  __shared__ float z1[200];
  __shared__ float z2[20];
  __shared__ float z3[4];
  for (int c=t;c<600;c+=256){
    float m = -1e30f;
#pragma unroll
    for (int rp=0;rp<8;rp++) m = fmaxf(m, part[(size_t)(g*8+rp)*600 + c]);
    gg[c] = m;
  }
  __syncthreads();
  if (t<200){
    float s = L1b[t];
#pragma unroll 4
    for (int k=0;k<600;k++) s += gg[k]*L1w[k*200+t];
    z1[t] = fmaxf(s,0.f);
  }
  __syncthreads();
  if (t<20){
    float s = L2b[t];
#pragma unroll 4
    for (int k=0;k<200;k++) s += z1[k]*L2w[k*20+t];
    z2[t] = fmaxf(s,0.f);
  }
  __syncthreads();
  if (t<4){
    float s = L3b[t];
    for (int k=0;k<20;k++) s += z2[k]*L3w[k*4+t];
    z3[t] = fmaxf(s,0.f);
  }
  __syncthreads();
  if (t==0){
    float m = fmaxf(fmaxf(z3[0],z3[1]), fmaxf(z3[2],z3[3]));
    float e0=expf(z3[0]-m), e1=expf(z3[1]-m), e2=expf(z3[2]-m), e3=expf(z3[3]-m);
    float s = e0+e1+e2+e3;
    out[g*4+0]=e0/s; out[g*4+1]=e1/s; out[g*4+2]=e2/s; out[g*4+3]=e3/s;
  }
}

// ---------- host orchestration ----------
struct WsPtrs {
  float *A, *B, *x0p, *W1p, *W2p;
  int *bsrc, *bdst, *bem, *beid;
  int *elist, *row_s, *row_e;
  int *inc, *inc_rs, *inc_re;
  float *dinv, *selfco, *aval, *bval;
  float *nscore; int *partner; int *valid;
  int *gcount;
  float *gbuf;
};

extern "C" void kernel_launch(void* const* d_in, const int* in_sizes, int n_in,
                              void* d_out, int out_size, void* d_ws, size_t ws_size,
                              hipStream_t stream){
  const float* x0  = (const float*)d_in[0];
  const int*   ei  = (const int*)  d_in[1];
  const float* W1  = (const float*)d_in[3];  const float* b1  = (const float*)d_in[4];
  const float* W2  = (const float*)d_in[5];  const float* b2  = (const float*)d_in[6];
  const float* W3  = (const float*)d_in[7];  const float* b3  = (const float*)d_in[8];
  const float* P1w = (const float*)d_in[9];  const float* P1b = (const float*)d_in[10];
  const float* P2w = (const float*)d_in[11]; const float* P2b = (const float*)d_in[12];
  const float* P3w = (const float*)d_in[13]; const float* P3b = (const float*)d_in[14];
  const float* L1w = (const float*)d_in[15]; const float* L1b = (const float*)d_in[16];
  const float* L2w = (const float*)d_in[17]; const float* L2b = (const float*)d_in[18];
  const float* L3w = (const float*)d_in[19]; const float* L3b = (const float*)d_in[20];
  float* out = (float*)d_out;

  char* w = (char*)d_ws;
  size_t off = 0;
  auto alloc = [&](size_t bytes)->void*{
    void* p = w + off;
    off += bytes;
    off = (off + 255) & ~(size_t)255;
    return p;
  };
  WsPtrs P;
  P.A     = (float*)alloc((size_t)NN*600*4);   // ping (also hosts dedupe table when h dead)
  P.B     = (float*)alloc((size_t)NN*600*4);   // pong
  P.x0p   = (float*)alloc((size_t)NN*112*4);
  P.W1p   = (float*)alloc((size_t)112*200*4);
  P.W2p   = (float*)alloc((size_t)208*400*4);
  P.bsrc  = (int*)  alloc((size_t)NGR*GSEG*4);
  P.bdst  = (int*)  alloc((size_t)NGR*GSEG*4);
  P.bem   = (int*)  alloc((size_t)NGR*GSEG*4);
  P.beid  = (int*)  alloc((size_t)NGR*GSEG*4);
  P.elist = (int*)  alloc((size_t)NGR*GSEG*4);
  P.inc   = (int*)  alloc((size_t)NGR*2*GSEG*4);
  P.inc_rs= (int*)  alloc((size_t)NN*4);
  P.inc_re= (int*)  alloc((size_t)NN*4);
  P.row_s = (int*)  alloc((size_t)NN*4);
  P.row_e = (int*)  alloc((size_t)NN*4);
  P.dinv   = (float*)alloc((size_t)NN*4);
  P.selfco = (float*)alloc((size_t)NN*4);
  P.aval   = (float*)alloc((size_t)NN*4);
  P.bval   = (float*)alloc((size_t)NN*4);
  P.nscore = (float*)alloc((size_t)NN*4);
  P.partner= (int*)  alloc((size_t)NN*4);
  P.valid  = (int*)  alloc((size_t)NN*4);
  P.gcount = (int*)  alloc((size_t)NGR*4);
  P.gbuf   = (float*)alloc((size_t)NGR*8*600*4);
  (void)ws_size; (void)in_sizes; (void)n_in; (void)out_size;

  const int NG4 = NN/4;

  // ---- one-time prep ----
  k_padx<<<(NN*112+255)/256,256,0,stream>>>(x0, P.x0p);
  k_padw<<<(112*200+255)/256,256,0,stream>>>(W1, P.W1p, 107, 112, 200);
  k_padw<<<(208*400+255)/256,256,0,stream>>>(W2, P.W2p, 200, 208, 400);
  hipMemsetAsync(P.gcount, 0, NGR*sizeof(int), stream);
  k_bucket<<<NE/256,256,0,stream>>>(ei, P.gcount, P.bsrc, P.bdst, P.bem, P.beid);
  k_init_nodes<<<NN/256,256,0,stream>>>(P.valid);

  // ---- layer 1: x0p[16384,112] -> h=A(200) -> y=B -> out1=A(stride 208) ----
  { dim3 gmm(4,128); k_mm<<<gmm,256,0,stream>>>(P.x0p, P.W1p, P.A, 112, 200); }
  k_prep<<<NGR,1024,0,stream>>>(P.bsrc,P.bdst,P.bem,P.gcount,P.row_s,P.row_e,P.elist,
                                P.inc,P.inc_rs,P.inc_re,P.dinv,P.selfco);
  k_aggab<200><<<NG4,256,0,stream>>>(P.A,P.row_s,P.row_e,P.elist,P.bsrc,P.dinv,P.selfco,b1,P1w,P.B,P.aval,P.bval);
  k_pool<<<NGR,1024,0,stream>>>(P.gcount,P.bsrc,P.bdst,P.bem,P.beid,P.inc,P.inc_rs,P.inc_re,
                                P.aval,P.bval,P1b,P.nscore,P.partner,P.valid,(int*)P.A);
  k_newx<200,208><<<NG4,256,0,stream>>>(P.B,P.partner,P.nscore,P.valid,P.A);

  // ---- layer 2: A[16384,208] -> h=B(400) -> y=A -> out2=B(stride 400) ----
  { dim3 gmm(7,128); k_mm<<<gmm,256,0,stream>>>(P.A, P.W2p, P.B, 208, 400); }
  k_prep<<<NGR,1024,0,stream>>>(P.bsrc,P.bdst,P.bem,P.gcount,P.row_s,P.row_e,P.elist,
                                P.inc,P.inc_rs,P.inc_re,P.dinv,P.selfco);
  k_aggab<400><<<NG4,256,0,stream>>>(P.B,P.row_s,P.row_e,P.elist,P.bsrc,P.dinv,P.selfco,b2,P2w,P.A,P.aval,P.bval);
  k_pool<<<NGR,1024,0,stream>>>(P.gcount,P.bsrc,P.bdst,P.bem,P.beid,P.inc,P.inc_rs,P.inc_re,
                                P.aval,P.bval,P2b,P.nscore,P.partner,P.valid,(int*)P.B);
  k_newx<400,400><<<NG4,256,0,stream>>>(P.A,P.partner,P.nscore,P.valid,P.B);

  // ---- layer 3: B[16384,400] -> h=A(600) -> y=B -> out3=A(stride 600) ----
  { dim3 gmm(10,128); k_mm<<<gmm,256,0,stream>>>(P.B, W3, P.A, 400, 600); }
  k_prep<<<NGR,1024,0,stream>>>(P.bsrc,P.bdst,P.bem,P.gcount,P.row_s,P.row_e,P.elist,
                                P.inc,P.inc_rs,P.inc_re,P.dinv,P.selfco);
  k_aggab<600><<<NG4,256,0,stream>>>(P.A,P.row_s,P.row_e,P.elist,P.bsrc,P.dinv,P.selfco,b3,P3w,P.B,P.aval,P.bval);
  k_pool<<<NGR,1024,0,stream>>>(P.gcount,P.bsrc,P.bdst,P.bem,P.beid,P.inc,P.inc_rs,P.inc_re,
                                P.aval,P.bval,P3b,P.nscore,P.partner,P.valid,(int*)P.A);
  k_newx<600,600><<<NG4,256,0,stream>>>(P.B,P.partner,P.nscore,P.valid,P.A);

  // ---- readout + MLP head + softmax ----
  k_gmax<<<NGR*8,256,0,stream>>>(P.A, P.valid, P.gbuf);
  k_head<<<NGR,256,0,stream>>>(P.gbuf, L1w, L1b, L2w, L2b, L3w, L3b, out);
}

// Round 8
// 2116.345 us; speedup vs baseline: 1.1667x; 1.1667x over previous
//
#include <hip/hip_runtime.h>

#define NN 16384
#define PERG 512
#define NGR 32
#define NE 262144
#define GSEG 9216            // per-graph edge segment capacity (max count ~8.6k)

// ---------- helpers ----------
__device__ __forceinline__ unsigned encf(float f){
  unsigned u = __float_as_uint(f);
  return (u & 0x80000000u) ? ~u : (u | 0x80000000u);
}
__device__ __forceinline__ float decf(unsigned e){
  unsigned u = (e & 0x80000000u) ? (e ^ 0x80000000u) : ~e;
  return __uint_as_float(u);
}

// ---------- one-time: pad copies for K%16==0 GEMMs ----------
__global__ void k_padx(const float* __restrict__ x, float* __restrict__ xp){
  int i = blockIdx.x*256 + threadIdx.x;          // over NN*112
  if (i < NN*112){ int r = i/112, c = i-r*112; xp[i] = (c<107) ? x[r*107+c] : 0.f; }
}
__global__ void k_padw(const float* __restrict__ Wsrc, float* __restrict__ Wdst,
                       int Ksrc, int Kdst, int N){
  int i = blockIdx.x*256 + threadIdx.x;
  if (i < Kdst*N){ int r = i/N, c = i-r*N; Wdst[i] = (r<Ksrc) ? Wsrc[r*N+c] : 0.f; }
}

// ---------- one-time bucketing: edges -> graph-major segments ----------
__global__ __launch_bounds__(256) void k_bucket(const int* __restrict__ ei, int* __restrict__ gcount,
    int* __restrict__ bsrc, int* __restrict__ bdst, int* __restrict__ bem, int* __restrict__ beid){
  __shared__ int cnt[NGR];
  __shared__ int base[NGR];
  int t = threadIdx.x;
  if (t < NGR) cnt[t] = 0;
  __syncthreads();
  int e = blockIdx.x*256 + t;
  int s=0,d=0,g=0,r=0;
  bool ok = (e < NE);
  if (ok){ s = ei[e]; d = ei[NE+e]; g = s >> 9; r = atomicAdd(&cnt[g],1); }
  __syncthreads();
  if (t < NGR) base[t] = atomicAdd(&gcount[t], cnt[t]);
  __syncthreads();
  if (ok){
    int pos = g*GSEG + base[g] + r;
    bsrc[pos]=s; bdst[pos]=d; bem[pos]=1; beid[pos]=e;
  }
}
__global__ void k_init_nodes(int* __restrict__ valid){
  int i = blockIdx.x*256 + threadIdx.x;
  if (i < NN) valid[i]=1;
}

// ---------- dense matmul C[M,N] = A[M,KP] @ W[KP,N], f32, KP%16==0 ----------
__global__ __launch_bounds__(256) void k_mm(const float* __restrict__ A, const float* __restrict__ W,
                                            float* __restrict__ C, int KP, int N){
  __shared__ float As[16][132];   // A transposed: As[k][row]
  __shared__ float Ws[16][68];
  int col0 = blockIdx.x*64, row0 = blockIdx.y*128;
  int t = threadIdx.x;
  int tx = t & 15, ty = t >> 4;
  int ar = t >> 1;
  int ak = (t & 1) * 8;
  int wk = t >> 4;
  int wn = (t & 15) * 4;
  int wc = col0 + wn;

  float acc[8][4];
#pragma unroll
  for (int i=0;i<8;i++)
#pragma unroll
    for (int j=0;j<4;j++) acc[i][j]=0.f;

  const float* Arow = A + (size_t)(row0+ar)*KP;

  for (int k0=0; k0<KP; k0+=16){
    float4 a0 = *(const float4*)&Arow[k0 + ak];
    float4 a1 = *(const float4*)&Arow[k0 + ak + 4];
    float4 w0;
    const float* wp = &W[(size_t)(k0+wk)*N + wc];
    if (wc+3 < N) w0 = *(const float4*)wp;
    else { w0.x=(wc<N)?wp[0]:0.f; w0.y=(wc+1<N)?wp[1]:0.f; w0.z=(wc+2<N)?wp[2]:0.f; w0.w=0.f; }
    __syncthreads();
    As[ak+0][ar]=a0.x; As[ak+1][ar]=a0.y; As[ak+2][ar]=a0.z; As[ak+3][ar]=a0.w;
    As[ak+4][ar]=a1.x; As[ak+5][ar]=a1.y; As[ak+6][ar]=a1.z; As[ak+7][ar]=a1.w;
    *(float4*)&Ws[wk][wn] = w0;
    __syncthreads();
#pragma unroll
    for (int kk=0;kk<16;kk++){
      float4 A0 = *(const float4*)&As[kk][ty*8];
      float4 A1 = *(const float4*)&As[kk][ty*8+4];
      float4 B0 = *(const float4*)&Ws[kk][tx*4];
      float a[8] = {A0.x,A0.y,A0.z,A0.w,A1.x,A1.y,A1.z,A1.w};
      float b[4] = {B0.x,B0.y,B0.z,B0.w};
#pragma unroll
      for (int i=0;i<8;i++)
#pragma unroll
        for (int j=0;j<4;j++) acc[i][j] += a[i]*b[j];
    }
  }

#pragma unroll
  for (int i=0;i<8;i++){
    int r = row0 + ty*8 + i;
    int cc = col0 + tx*4;
    if (cc+3 < N){
      float4 v = {acc[i][0],acc[i][1],acc[i][2],acc[i][3]};
      *(float4*)&C[(size_t)r*N+cc] = v;
    } else {
#pragma unroll
      for (int j=0;j<4;j++) if (cc+j<N) C[(size_t)r*N+cc+j] = acc[i][j];
    }
  }
}

// ---------- per-graph CSR (by dst) + node incidence lists + node prep ----------
__global__ __launch_bounds__(1024) void k_prep(const int* __restrict__ bsrc, const int* __restrict__ bdst,
    const int* __restrict__ bem, const int* __restrict__ gcount,
    int* __restrict__ row_s, int* __restrict__ row_e, int* __restrict__ elist,
    int* __restrict__ inc, int* __restrict__ inc_rs, int* __restrict__ inc_re,
    float* __restrict__ dinv, float* __restrict__ selfco){
  int g = blockIdx.x, t = threadIdx.x;
  __shared__ int cnt_l[PERG];
  __shared__ int cnt2[PERG];
  __shared__ int scn[PERG];
  __shared__ int cur[PERG];
  __shared__ int cur2[PERG];
  __shared__ unsigned char hs_l[PERG];
  if (t<PERG){ cnt_l[t]=0; cnt2[t]=0; hs_l[t]=0; }
  __syncthreads();
  int nE = min(gcount[g], GSEG); int base = g*GSEG; int base2 = g*2*GSEG;
  for (int k=t;k<nE;k+=1024){
    if (bem[base+k]){
      int d = bdst[base+k]&511, s = bsrc[base+k]&511;
      atomicAdd(&cnt_l[d],1);
      if (s==d) hs_l[d]=1;
      atomicAdd(&cnt2[d],1);
      atomicAdd(&cnt2[s],1);
    }
  }
  __syncthreads();
  // scan 1: dst-CSR
  if (t<PERG) scn[t]=cnt_l[t];
  __syncthreads();
  for (int off=1; off<PERG; off<<=1){
    int v = (t<PERG && t>=off) ? scn[t-off] : 0;
    __syncthreads();
    if (t<PERG) scn[t]+=v;
    __syncthreads();
  }
  if (t<PERG){
    int excl = scn[t]-cnt_l[t];
    row_s[g*PERG+t] = base+excl;
    row_e[g*PERG+t] = base+scn[t];
    cur[t] = excl;
    float deg = (float)cnt_l[t] + (hs_l[t]?0.f:1.f);
    dinv[g*PERG+t]   = rsqrtf(deg);
    selfco[g*PERG+t] = hs_l[t]?0.f:(1.f/deg);
  }
  __syncthreads();
  // scan 2: incidence offsets
  if (t<PERG) scn[t]=cnt2[t];
  __syncthreads();
  for (int off=1; off<PERG; off<<=1){
    int v = (t<PERG && t>=off) ? scn[t-off] : 0;
    __syncthreads();
    if (t<PERG) scn[t]+=v;
    __syncthreads();
  }
  if (t<PERG){
    int excl = scn[t]-cnt2[t];
    inc_rs[g*PERG+t] = base2+excl;
    inc_re[g*PERG+t] = base2+scn[t];
    cur2[t] = excl;
  }
  __syncthreads();
  for (int k=t;k<nE;k+=1024){
    if (bem[base+k]){
      int d = bdst[base+k]&511, s = bsrc[base+k]&511;
      elist[base + atomicAdd(&cur[d],1)] = base+k;
      inc[base2 + atomicAdd(&cur2[d],1)] = (s<<14)|k;
      inc[base2 + atomicAdd(&cur2[s],1)] = (d<<14)|k;
    }
  }
}

// ---------- GCN agg + bias + pool-score partials (fused; XCD-swizzled) ----------
template<int FO>
__global__ __launch_bounds__(256) void k_aggab(const float* __restrict__ h, const int* __restrict__ row_s,
    const int* __restrict__ row_e, const int* __restrict__ elist, const int* __restrict__ bsrc,
    const float* __restrict__ dinv, const float* __restrict__ selfco, const float* __restrict__ bias,
    const float* __restrict__ Pw, float* __restrict__ y, float* __restrict__ aval, float* __restrict__ bval){
  constexpr int Q = (FO+63)/64;
  int lane = threadIdx.x & 63;
  int nblk = (blockIdx.x & 7)*512 + (blockIdx.x >> 3);
  int i = nblk*4 + (threadIdx.x>>6);
  float acc[Q];
#pragma unroll
  for (int q=0;q<Q;q++) acc[q]=0.f;
  int s0 = row_s[i], s1 = row_e[i];
  float di = dinv[i];
  for (int p=s0; p<s1; p++){
    int e = elist[p]; int s = bsrc[e];
    float nr = di * dinv[s];
    const float* hrow = h + (size_t)s*FO;
#pragma unroll
    for (int q=0;q<Q;q++){ int c=lane+q*64; if (c<FO) acc[q] += nr*hrow[c]; }
  }
  float sc = selfco[i];
  const float* hi = h + (size_t)i*FO;
  float* yi = y + (size_t)i*FO;
  float sa=0.f, sb=0.f;
#pragma unroll
  for (int q=0;q<Q;q++){
    int c = lane+q*64;
    if (c<FO){
      float v = acc[q] + sc*hi[c] + bias[c];
      yi[c] = v;
      sa += v*Pw[c];
      sb += v*Pw[FO+c];
    }
  }
  for (int o=32;o;o>>=1){ sa += __shfl_xor(sa,o); sb += __shfl_xor(sb,o); }
  if (lane==0){ aval[i]=sa; bval[i]=sb; }
}

// ---------- pool: softmax + node-centric greedy match (LDS-resident) + remap + dedupe ----------
#define NEPT 9   // 9 * 1024 = 9216 = GSEG
__global__ __launch_bounds__(1024) void k_pool(const int* __restrict__ gcount,
    int* __restrict__ bsrc, int* __restrict__ bdst, int* __restrict__ bem, const int* __restrict__ beid,
    const int* __restrict__ inc, const int* __restrict__ inc_rs, const int* __restrict__ inc_re,
    const float* __restrict__ aval, const float* __restrict__ bval, const float* __restrict__ Pb,
    float* __restrict__ nscore, int* __restrict__ partner, int* __restrict__ valid, int* __restrict__ table){
  // dynamic LDS: incidence copy (2*GSEG u32) + per-edge score bits (GSEG u32) = 110.6 KB
  extern __shared__ unsigned smemU[];
  unsigned* incL = smemU;            // [2*GSEG]
  unsigned* sbl  = smemU + 2*GSEG;   // [GSEG]
  __shared__ unsigned mx[PERG];
  __shared__ float den[PERG];
  __shared__ unsigned char marked[PERG];
  __shared__ unsigned short clus[PERG];
  __shared__ unsigned short best_e[PERG];
  __shared__ unsigned short best_o[PERG];
  __shared__ int rsL[PERG];
  __shared__ int reL[PERG];
  __shared__ int flag;
  int g = blockIdx.x, t = threadIdx.x;
  int nE = min(gcount[g], GSEG), base = g*GSEG, base2 = g*2*GSEG;
  if (t<PERG){
    mx[t]=0u; den[t]=0.f;
    marked[t] = valid[(g<<9)+t] ? 0 : 1;
    clus[t] = (unsigned short)t;
    nscore[(g<<9)+t] = 1.f;
    partner[(g<<9)+t] = -1;
    rsL[t] = inc_rs[(g<<9)+t] - base2;
    reL[t] = inc_re[(g<<9)+t] - base2;
  }
  __syncthreads();
  // copy incidence lists into LDS (coalesced, one-time)
  int totInc = reL[PERG-1];
  for (int j=t; j<totInc; j+=1024) incL[j] = (unsigned)inc[base2+j];

  // ---- softmax over edges grouped by dst (scores -> sbl) ----
  int sL[NEPT], dL[NEPT];
  float rawv[NEPT];
  unsigned em = 0u;
#pragma unroll
  for (int j=0;j<NEPT;j++){
    sL[j]=0; dL[j]=0; rawv[j]=0.f;
    int k = t + j*1024;
    if (k < nE && bem[base+k]){
      sL[j] = bsrc[base+k]&511; dL[j] = bdst[base+k]&511;
      rawv[j] = aval[(g<<9)+sL[j]] + bval[(g<<9)+dL[j]] + Pb[0];
      em |= (1u<<j);
      atomicMax(&mx[dL[j]], encf(rawv[j]));
    }
  }
  __syncthreads();
  float exv[NEPT];
#pragma unroll
  for (int j=0;j<NEPT;j++){
    exv[j]=0.f;
    if (em & (1u<<j)){
      exv[j] = expf(rawv[j] - decf(mx[dL[j]]));
      atomicAdd(&den[dL[j]], exv[j]);
    }
  }
  __syncthreads();
#pragma unroll
  for (int j=0;j<NEPT;j++){
    if (em & (1u<<j)){
      int k = t + j*1024;
      float sc = exv[j]/fmaxf(den[dL[j]],1e-16f) + 0.1f;
      sbl[k] = __float_as_uint(sc);
    }
  }
  __syncthreads();

  // ---- greedy matching: per-node LDS scan (no atomics, no global traffic) ----
  for (int round=0; round<600; ++round){
    if (t<PERG){ best_e[t]=0xFFFF; best_o[t]=0xFFFF; }
    if (t==0) flag = 0;
    __syncthreads();
    if (t<PERG && !marked[t]){
      int n = t;
      unsigned bsb = 0u; int bk = -1, bo = 0; unsigned bbe = 0xFFFFFFFFu;
      int j1 = reL[n];
      for (int j=rsL[n]; j<j1; j++){
        unsigned en = incL[j];
        int o = en>>14, k_ = en & 0x3FFF;
        if (marked[o]) continue;
        unsigned sv = sbl[k_];
        if (sv < bsb) continue;
        if (sv > bsb){ bsb=sv; bk=k_; bo=o; bbe=0xFFFFFFFFu; }
        else {
          if (bbe==0xFFFFFFFFu) bbe = (unsigned)beid[base+bk];   // rare: exact ties only
          unsigned nb = (unsigned)beid[base+k_];
          if (nb < bbe){ bk=k_; bo=o; bbe=nb; }
        }
      }
      if (bk>=0){ best_e[n]=(unsigned short)bk; best_o[n]=(unsigned short)bo; flag=1; }
    }
    __syncthreads();
    if (!flag) break;
    if (t<PERG && !marked[t]){
      int n = t;
      int bk = best_e[n];
      if (bk != 0xFFFF){
        int o = best_o[n];
        if (o == n){                      // self-loop: mark node, score it
          nscore[(g<<9)+n] = __uint_as_float(sbl[bk]);
          marked[n] = 1;
        } else if (best_e[o]==bk && n<o){ // mutual max: contract o into n
          clus[o] = (unsigned short)n;
          nscore[(g<<9)+n] = __uint_as_float(sbl[bk]);
          valid[(g<<9)+o] = 0;
          partner[(g<<9)+n] = (g<<9)+o;
          marked[n] = 1; marked[o] = 1;
        }
      }
    }
    __syncthreads();
  }
  __syncthreads();

  // ---- remap + dedupe (graph-local key table in global scratch) ----
#pragma unroll
  for (int j=0;j<NEPT;j++){
    if (em & (1u<<j)){
      int k = t + j*1024;
      int ns = clus[sL[j]], nd = clus[dL[j]];
      sL[j]=ns; dL[j]=nd;
      bsrc[base+k] = (g<<9)+ns; bdst[base+k] = (g<<9)+nd;
      table[(g<<18) | (ns<<9) | nd] = 0x7FFFFFFF;
    }
  }
  __syncthreads();
#pragma unroll
  for (int j=0;j<NEPT;j++){
    if (em & (1u<<j)){
      int k = t + j*1024;
      atomicMin(&table[(g<<18) | (sL[j]<<9) | dL[j]], base+k);
    }
  }
  __syncthreads();
#pragma unroll
  for (int j=0;j<NEPT;j++){
    if (em & (1u<<j)){
      int k = t + j*1024;
      if (table[(g<<18) | (sL[j]<<9) | dL[j]] != base+k) bem[base+k] = 0;
    }
  }
}

// ---------- pool: new_x = relu((y[i]+y[partner]) * score * valid), pad-zeroed ----------
template<int FO, int FOP>
__global__ __launch_bounds__(256) void k_newx(const float* __restrict__ y, const int* __restrict__ partner,
    const float* __restrict__ nscore, const int* __restrict__ valid, float* __restrict__ out){
  constexpr int Q = (FOP+63)/64;
  int lane = threadIdx.x & 63;
  int nblk = (blockIdx.x & 7)*512 + (blockIdx.x >> 3);
  int i = nblk*4 + (threadIdx.x>>6);
  int v = valid[i];
  float ns = nscore[i];
  int p = partner[i];
  const float* yi = y + (size_t)i*FO;
  const float* yp = (p>=0) ? (y + (size_t)p*FO) : yi;
  float* oi = out + (size_t)i*FOP;
#pragma unroll
  for (int q=0;q<Q;q++){
    int c = lane + q*64;
    if (c<FO){
      float val = yi[c];
      if (p>=0) val += yp[c];
      val *= ns;
      oi[c] = v ? fmaxf(val,0.f) : 0.f;
    } else if (c<FOP){
      oi[c] = 0.f;
    }
  }
}

// ---------- readout: stage 1, per-(graph, 64-row part) partial max ----------
__global__ __launch_bounds__(256) void k_gmax(const float* __restrict__ x, const int* __restrict__ valid,
                                              float* __restrict__ part){
  int g = blockIdx.x >> 3, rp = blockIdx.x & 7;
  __shared__ int lv[64];
  int r0 = rp*64;
  if (threadIdx.x < 64) lv[threadIdx.x] = valid[g*PERG + r0 + threadIdx.x];
  __syncthreads();
  const float* base = x + ((size_t)g*PERG + r0)*600;
  for (int c=threadIdx.x; c<600; c+=256){
    float m = -1e30f;
    for (int r=0;r<64;r++)
      if (lv[r]) m = fmaxf(m, base[(size_t)r*600+c]);
    part[(size_t)(g*8+rp)*600 + c] = m;
  }
}
__global__ __launch_bounds__(256) void k_head(const float* __restrict__ part,
    const float* __restrict__ L1w, const float* __restrict__ L1b,
    const float* __restrict__ L2w, const float* __restrict__ L2b,
    const float* __restrict__ L3w, const float* __restrict__ L3b, float* __restrict__ out){
  int g = blockIdx.x, t = threadIdx.x;
  __shared__ float gg[600];
  __shared__ float z1[200];
  __shared__ float z2[20];
  __shared__ float z3[4];
  for (int c=t;c<600;c+=256){
    float m = -1e30f;
#pragma unroll
    for (int rp=0;rp<8;rp++) m = fmaxf(m, part[(size_t)(g*8+rp)*600 + c]);
    gg[c] = m;
  }
  __syncthreads();
  if (t<200){
    float s = L1b[t];
#pragma unroll 4
    for (int k=0;k<600;k++) s += gg[k]*L1w[k*200+t];
    z1[t] = fmaxf(s,0.f);
  }
  __syncthreads();
  if (t<20){
    float s = L2b[t];
#pragma unroll 4
    for (int k=0;k<200;k++) s += z1[k]*L2w[k*20+t];
    z2[t] = fmaxf(s,0.f);
  }
  __syncthreads();
  if (t<4){
    float s = L3b[t];
    for (int k=0;k<20;k++) s += z2[k]*L3w[k*4+t];
    z3[t] = fmaxf(s,0.f);
  }
  __syncthreads();
  if (t==0){
    float m = fmaxf(fmaxf(z3[0],z3[1]), fmaxf(z3[2],z3[3]));
    float e0=expf(z3[0]-m), e1=expf(z3[1]-m), e2=expf(z3[2]-m), e3=expf(z3[3]-m);
    float s = e0+e1+e2+e3;
    out[g*4+0]=e0/s; out[g*4+1]=e1/s; out[g*4+2]=e2/s; out[g*4+3]=e3/s;
  }
}

// ---------- host orchestration ----------
struct WsPtrs {
  float *A, *B, *x0p, *W1p, *W2p;
  int *bsrc, *bdst, *bem, *beid;
  int *elist, *row_s, *row_e;
  int *inc, *inc_rs, *inc_re;
  float *dinv, *selfco, *aval, *bval;
  float *nscore; int *partner; int *valid;
  int *gcount;
  float *gbuf;
};

extern "C" void kernel_launch(void* const* d_in, const int* in_sizes, int n_in,
                              void* d_out, int out_size, void* d_ws, size_t ws_size,
                              hipStream_t stream){
  const float* x0  = (const float*)d_in[0];
  const int*   ei  = (const int*)  d_in[1];
  const float* W1  = (const float*)d_in[3];  const float* b1  = (const float*)d_in[4];
  const float* W2  = (const float*)d_in[5];  const float* b2  = (const float*)d_in[6];
  const float* W3  = (const float*)d_in[7];  const float* b3  = (const float*)d_in[8];
  const float* P1w = (const float*)d_in[9];  const float* P1b = (const float*)d_in[10];
  const float* P2w = (const float*)d_in[11]; const float* P2b = (const float*)d_in[12];
  const float* P3w = (const float*)d_in[13]; const float* P3b = (const float*)d_in[14];
  const float* L1w = (const float*)d_in[15]; const float* L1b = (const float*)d_in[16];
  const float* L2w = (const float*)d_in[17]; const float* L2b = (const float*)d_in[18];
  const float* L3w = (const float*)d_in[19]; const float* L3b = (const float*)d_in[20];
  float* out = (float*)d_out;

  char* w = (char*)d_ws;
  size_t off = 0;
  auto alloc = [&](size_t bytes)->void*{
    void* p = w + off;
    off += bytes;
    off = (off + 255) & ~(size_t)255;
    return p;
  };
  WsPtrs P;
  P.A     = (float*)alloc((size_t)NN*600*4);   // ping (also hosts dedupe table when h dead)
  P.B     = (float*)alloc((size_t)NN*600*4);   // pong
  P.x0p   = (float*)alloc((size_t)NN*112*4);
  P.W1p   = (float*)alloc((size_t)112*200*4);
  P.W2p   = (float*)alloc((size_t)208*400*4);
  P.bsrc  = (int*)  alloc((size_t)NGR*GSEG*4);
  P.bdst  = (int*)  alloc((size_t)NGR*GSEG*4);
  P.bem   = (int*)  alloc((size_t)NGR*GSEG*4);
  P.beid  = (int*)  alloc((size_t)NGR*GSEG*4);
  P.elist = (int*)  alloc((size_t)NGR*GSEG*4);
  P.inc   = (int*)  alloc((size_t)NGR*2*GSEG*4);
  P.inc_rs= (int*)  alloc((size_t)NN*4);
  P.inc_re= (int*)  alloc((size_t)NN*4);
  P.row_s = (int*)  alloc((size_t)NN*4);
  P.row_e = (int*)  alloc((size_t)NN*4);
  P.dinv   = (float*)alloc((size_t)NN*4);
  P.selfco = (float*)alloc((size_t)NN*4);
  P.aval   = (float*)alloc((size_t)NN*4);
  P.bval   = (float*)alloc((size_t)NN*4);
  P.nscore = (float*)alloc((size_t)NN*4);
  P.partner= (int*)  alloc((size_t)NN*4);
  P.valid  = (int*)  alloc((size_t)NN*4);
  P.gcount = (int*)  alloc((size_t)NGR*4);
  P.gbuf   = (float*)alloc((size_t)NGR*8*600*4);
  (void)ws_size; (void)in_sizes; (void)n_in; (void)out_size;

  const int NG4 = NN/4;
  const int POOL_LDS = (2*GSEG + GSEG) * 4;   // 110,592 B dynamic LDS

  // ---- one-time prep ----
  k_padx<<<(NN*112+255)/256,256,0,stream>>>(x0, P.x0p);
  k_padw<<<(112*200+255)/256,256,0,stream>>>(W1, P.W1p, 107, 112, 200);
  k_padw<<<(208*400+255)/256,256,0,stream>>>(W2, P.W2p, 200, 208, 400);
  hipMemsetAsync(P.gcount, 0, NGR*sizeof(int), stream);
  k_bucket<<<NE/256,256,0,stream>>>(ei, P.gcount, P.bsrc, P.bdst, P.bem, P.beid);
  k_init_nodes<<<NN/256,256,0,stream>>>(P.valid);

  // ---- layer 1: x0p[16384,112] -> h=A(200) -> y=B -> out1=A(stride 208) ----
  { dim3 gmm(4,128); k_mm<<<gmm,256,0,stream>>>(P.x0p, P.W1p, P.A, 112, 200); }
  k_prep<<<NGR,1024,0,stream>>>(P.bsrc,P.bdst,P.bem,P.gcount,P.row_s,P.row_e,P.elist,
                                P.inc,P.inc_rs,P.inc_re,P.dinv,P.selfco);
  k_aggab<200><<<NG4,256,0,stream>>>(P.A,P.row_s,P.row_e,P.elist,P.bsrc,P.dinv,P.selfco,b1,P1w,P.B,P.aval,P.bval);
  k_pool<<<NGR,1024,POOL_LDS,stream>>>(P.gcount,P.bsrc,P.bdst,P.bem,P.beid,P.inc,P.inc_rs,P.inc_re,
                                P.aval,P.bval,P1b,P.nscore,P.partner,P.valid,(int*)P.A);
  k_newx<200,208><<<NG4,256,0,stream>>>(P.B,P.partner,P.nscore,P.valid,P.A);

  // ---- layer 2: A[16384,208] -> h=B(400) -> y=A -> out2=B(stride 400) ----
  { dim3 gmm(7,128); k_mm<<<gmm,256,0,stream>>>(P.A, P.W2p, P.B, 208, 400); }
  k_prep<<<NGR,1024,0,stream>>>(P.bsrc,P.bdst,P.bem,P.gcount,P.row_s,P.row_e,P.elist,
                                P.inc,P.inc_rs,P.inc_re,P.dinv,P.selfco);
  k_aggab<400><<<NG4,256,0,stream>>>(P.B,P.row_s,P.row_e,P.elist,P.bsrc,P.dinv,P.selfco,b2,P2w,P.A,P.aval,P.bval);
  k_pool<<<NGR,1024,POOL_LDS,stream>>>(P.gcount,P.bsrc,P.bdst,P.bem,P.beid,P.inc,P.inc_rs,P.inc_re,
                                P.aval,P.bval,P2b,P.nscore,P.partner,P.valid,(int*)P.B);
  k_newx<400,400><<<NG4,256,0,stream>>>(P.A,P.partner,P.nscore,P.valid,P.B);

  // ---- layer 3: B[16384,400] -> h=A(600) -> y=B -> out3=A(stride 600) ----
  { dim3 gmm(10,128); k_mm<<<gmm,256,0,stream>>>(P.B, W3, P.A, 400, 600); }
  k_prep<<<NGR,1024,0,stream>>>(P.bsrc,P.bdst,P.bem,P.gcount,P.row_s,P.row_e,P.elist,
                                P.inc,P.inc_rs,P.inc_re,P.dinv,P.selfco);
  k_aggab<600><<<NG4,256,0,stream>>>(P.A,P.row_s,P.row_e,P.elist,P.bsrc,P.dinv,P.selfco,b3,P3w,P.B,P.aval,P.bval);
  k_pool<<<NGR,1024,POOL_LDS,stream>>>(P.gcount,P.bsrc,P.bdst,P.bem,P.beid,P.inc,P.inc_rs,P.inc_re,
                                P.aval,P.bval,P3b,P.nscore,P.partner,P.valid,(int*)P.A);
  k_newx<600,600><<<NG4,256,0,stream>>>(P.B,P.partner,P.nscore,P.valid,P.A);

  // ---- readout + MLP head + softmax ----
  k_gmax<<<NGR*8,256,0,stream>>>(P.A, P.valid, P.gbuf);
  k_head<<<NGR,256,0,stream>>>(P.gbuf, L1w, L1b, L2w, L2b, L3w, L3b, out);
}

// Round 10
// 1682.960 us; speedup vs baseline: 1.4671x; 1.2575x over previous
//
#include <hip/hip_runtime.h>

#define NN 16384
#define PERG 512
#define NGR 32
#define NE 262144
#define GSEG 9216            // per-graph edge segment capacity (max count ~8.6k)
#define NSORT 16384          // pow2 >= GSEG for bitonic

typedef unsigned long long u64;

// ---------- helpers ----------
__device__ __forceinline__ unsigned encf(float f){
  unsigned u = __float_as_uint(f);
  return (u & 0x80000000u) ? ~u : (u | 0x80000000u);
}
__device__ __forceinline__ float decf(unsigned e){
  unsigned u = (e & 0x80000000u) ? (e ^ 0x80000000u) : ~e;
  return __uint_as_float(u);
}

// ---------- one-time: pad copies for K%16==0 GEMMs ----------
__global__ void k_padx(const float* __restrict__ x, float* __restrict__ xp){
  int i = blockIdx.x*256 + threadIdx.x;          // over NN*112
  if (i < NN*112){ int r = i/112, c = i-r*112; xp[i] = (c<107) ? x[r*107+c] : 0.f; }
}
__global__ void k_padw(const float* __restrict__ Wsrc, float* __restrict__ Wdst,
                       int Ksrc, int Kdst, int N){
  int i = blockIdx.x*256 + threadIdx.x;
  if (i < Kdst*N){ int r = i/N, c = i-r*N; Wdst[i] = (r<Ksrc) ? Wsrc[r*N+c] : 0.f; }
}

// ---------- one-time bucketing: edges -> graph-major segments ----------
__global__ __launch_bounds__(256) void k_bucket(const int* __restrict__ ei, int* __restrict__ gcount,
    int* __restrict__ bsrc, int* __restrict__ bdst, int* __restrict__ bem, int* __restrict__ beid){
  __shared__ int cnt[NGR];
  __shared__ int base[NGR];
  int t = threadIdx.x;
  if (t < NGR) cnt[t] = 0;
  __syncthreads();
  int e = blockIdx.x*256 + t;
  int s=0,d=0,g=0,r=0;
  bool ok = (e < NE);
  if (ok){ s = ei[e]; d = ei[NE+e]; g = s >> 9; r = atomicAdd(&cnt[g],1); }
  __syncthreads();
  if (t < NGR) base[t] = atomicAdd(&gcount[t], cnt[t]);
  __syncthreads();
  if (ok){
    int pos = g*GSEG + base[g] + r;
    bsrc[pos]=s; bdst[pos]=d; bem[pos]=1; beid[pos]=e;
  }
}
__global__ void k_init_nodes(int* __restrict__ valid){
  int i = blockIdx.x*256 + threadIdx.x;
  if (i < NN) valid[i]=1;
}

// ---------- dense matmul C[M,N] = A[M,KP] @ W[KP,N], f32, KP%16==0 ----------
__global__ __launch_bounds__(256) void k_mm(const float* __restrict__ A, const float* __restrict__ W,
                                            float* __restrict__ C, int KP, int N){
  __shared__ float As[16][132];   // A transposed: As[k][row]
  __shared__ float Ws[16][68];
  int col0 = blockIdx.x*64, row0 = blockIdx.y*128;
  int t = threadIdx.x;
  int tx = t & 15, ty = t >> 4;
  int ar = t >> 1;
  int ak = (t & 1) * 8;
  int wk = t >> 4;
  int wn = (t & 15) * 4;
  int wc = col0 + wn;

  float acc[8][4];
#pragma unroll
  for (int i=0;i<8;i++)
#pragma unroll
    for (int j=0;j<4;j++) acc[i][j]=0.f;

  const float* Arow = A + (size_t)(row0+ar)*KP;

  for (int k0=0; k0<KP; k0+=16){
    float4 a0 = *(const float4*)&Arow[k0 + ak];
    float4 a1 = *(const float4*)&Arow[k0 + ak + 4];
    float4 w0;
    const float* wp = &W[(size_t)(k0+wk)*N + wc];
    if (wc+3 < N) w0 = *(const float4*)wp;
    else { w0.x=(wc<N)?wp[0]:0.f; w0.y=(wc+1<N)?wp[1]:0.f; w0.z=(wc+2<N)?wp[2]:0.f; w0.w=0.f; }
    __syncthreads();
    As[ak+0][ar]=a0.x; As[ak+1][ar]=a0.y; As[ak+2][ar]=a0.z; As[ak+3][ar]=a0.w;
    As[ak+4][ar]=a1.x; As[ak+5][ar]=a1.y; As[ak+6][ar]=a1.z; As[ak+7][ar]=a1.w;
    *(float4*)&Ws[wk][wn] = w0;
    __syncthreads();
#pragma unroll
    for (int kk=0;kk<16;kk++){
      float4 A0 = *(const float4*)&As[kk][ty*8];
      float4 A1 = *(const float4*)&As[kk][ty*8+4];
      float4 B0 = *(const float4*)&Ws[kk][tx*4];
      float a[8] = {A0.x,A0.y,A0.z,A0.w,A1.x,A1.y,A1.z,A1.w};
      float b[4] = {B0.x,B0.y,B0.z,B0.w};
#pragma unroll
      for (int i=0;i<8;i++)
#pragma unroll
        for (int j=0;j<4;j++) acc[i][j] += a[i]*b[j];
    }
  }

#pragma unroll
  for (int i=0;i<8;i++){
    int r = row0 + ty*8 + i;
    int cc = col0 + tx*4;
    if (cc+3 < N){
      float4 v = {acc[i][0],acc[i][1],acc[i][2],acc[i][3]};
      *(float4*)&C[(size_t)r*N+cc] = v;
    } else {
#pragma unroll
      for (int j=0;j<4;j++) if (cc+j<N) C[(size_t)r*N+cc+j] = acc[i][j];
    }
  }
}

// ---------- per-graph CSR (by dst) + node prep; elist stores SRC node id ----------
__global__ __launch_bounds__(1024) void k_prep(const int* __restrict__ bsrc, const int* __restrict__ bdst,
    const int* __restrict__ bem, const int* __restrict__ gcount,
    int* __restrict__ row_s, int* __restrict__ row_e, int* __restrict__ elist,
    float* __restrict__ dinv, float* __restrict__ selfco){
  int g = blockIdx.x, t = threadIdx.x;
  __shared__ int cnt_l[PERG];
  __shared__ int scn[PERG];
  __shared__ int cur[PERG];
  __shared__ unsigned char hs_l[PERG];
  if (t<PERG){ cnt_l[t]=0; hs_l[t]=0; }
  __syncthreads();
  int nE = min(gcount[g], GSEG); int base = g*GSEG;
  for (int k=t;k<nE;k+=1024){
    if (bem[base+k]){
      int d = bdst[base+k]&511;
      atomicAdd(&cnt_l[d],1);
      if (bsrc[base+k]==bdst[base+k]) hs_l[d]=1;
    }
  }
  __syncthreads();
  if (t<PERG) scn[t]=cnt_l[t];
  __syncthreads();
  for (int off=1; off<PERG; off<<=1){
    int v = (t<PERG && t>=off) ? scn[t-off] : 0;
    __syncthreads();
    if (t<PERG) scn[t]+=v;
    __syncthreads();
  }
  if (t<PERG){
    int excl = scn[t]-cnt_l[t];
    row_s[g*PERG+t] = base+excl;
    row_e[g*PERG+t] = base+scn[t];
    cur[t] = excl;
    float deg = (float)cnt_l[t] + (hs_l[t]?0.f:1.f);
    dinv[g*PERG+t]   = rsqrtf(deg);
    selfco[g*PERG+t] = hs_l[t]?0.f:(1.f/deg);
  }
  __syncthreads();
  for (int k=t;k<nE;k+=1024){
    if (bem[base+k]){
      int d = bdst[base+k]&511;
      elist[base + atomicAdd(&cur[d],1)] = bsrc[base+k];   // src node id directly
    }
  }
}

// ---------- GCN agg + bias + pool-score partials (fused; XCD-swizzled) ----------
template<int FO>
__global__ __launch_bounds__(256) void k_aggab(const float* __restrict__ h, const int* __restrict__ row_s,
    const int* __restrict__ row_e, const int* __restrict__ elist,
    const float* __restrict__ dinv, const float* __restrict__ selfco, const float* __restrict__ bias,
    const float* __restrict__ Pw, float* __restrict__ y, float* __restrict__ aval, float* __restrict__ bval){
  constexpr int Q = (FO+63)/64;
  int lane = threadIdx.x & 63;
  int nblk = (blockIdx.x & 7)*512 + (blockIdx.x >> 3);
  int i = nblk*4 + (threadIdx.x>>6);
  float acc[Q];
#pragma unroll
  for (int q=0;q<Q;q++) acc[q]=0.f;
  int s0 = row_s[i], s1 = row_e[i];
  float di = dinv[i];
  for (int p=s0; p<s1; p++){
    int s = elist[p];
    float nr = di * dinv[s];
    const float* hrow = h + (size_t)s*FO;
#pragma unroll
    for (int q=0;q<Q;q++){ int c=lane+q*64; if (c<FO) acc[q] += nr*hrow[c]; }
  }
  float sc = selfco[i];
  const float* hi = h + (size_t)i*FO;
  float* yi = y + (size_t)i*FO;
  float sa=0.f, sb=0.f;
#pragma unroll
  for (int q=0;q<Q;q++){
    int c = lane+q*64;
    if (c<FO){
      float v = acc[q] + sc*hi[c] + bias[c];
      yi[c] = v;
      sa += v*Pw[c];
      sb += v*Pw[FO+c];
    }
  }
  for (int o=32;o;o>>=1){ sa += __shfl_xor(sa,o); sb += __shfl_xor(sb,o); }
  if (lane==0){ aval[i]=sa; bval[i]=sb; }
}

// ---------- pool: softmax + SORT + single ordered greedy scan + remap + dedupe ----------
#define NEPT 9   // 9 * 1024 = 9216 = GSEG
__global__ __launch_bounds__(1024) void k_pool(const int* __restrict__ gcount,
    int* __restrict__ bsrc, int* __restrict__ bdst, int* __restrict__ bem, const int* __restrict__ beid,
    const float* __restrict__ aval, const float* __restrict__ bval, const float* __restrict__ Pb,
    float* __restrict__ nscore, int* __restrict__ partner, int* __restrict__ valid, int* __restrict__ table){
  extern __shared__ u64 skL[];            // [NSORT] = 128 KB
  __shared__ unsigned mx[PERG];
  __shared__ float den[PERG];
  __shared__ unsigned char marked[PERG];
  __shared__ unsigned short clus[PERG];
  int g = blockIdx.x, t = threadIdx.x;
  int nE = min(gcount[g], GSEG), base = g*GSEG;
  if (t<PERG){
    mx[t]=0u; den[t]=0.f;
    marked[t] = valid[(g<<9)+t] ? 0 : 1;
    clus[t] = (unsigned short)t;
    nscore[(g<<9)+t] = 1.f;
    partner[(g<<9)+t] = -1;
  }
#pragma unroll
  for (int q=0;q<NSORT/1024;q++) skL[t + q*1024] = 0ull;
  __syncthreads();

  // ---- softmax over edges grouped by dst ----
  int sL[NEPT], dL[NEPT];
  float rawv[NEPT];
  unsigned em = 0u;
#pragma unroll
  for (int j=0;j<NEPT;j++){
    sL[j]=0; dL[j]=0; rawv[j]=0.f;
    int k = t + j*1024;
    if (k < nE && bem[base+k]){
      sL[j] = bsrc[base+k]&511; dL[j] = bdst[base+k]&511;
      rawv[j] = aval[(g<<9)+sL[j]] + bval[(g<<9)+dL[j]] + Pb[0];
      em |= (1u<<j);
      atomicMax(&mx[dL[j]], encf(rawv[j]));
    }
  }
  __syncthreads();
  float exv[NEPT];
#pragma unroll
  for (int j=0;j<NEPT;j++){
    exv[j]=0.f;
    if (em & (1u<<j)){
      exv[j] = expf(rawv[j] - decf(mx[dL[j]]));
      atomicAdd(&den[dL[j]], exv[j]);
    }
  }
  __syncthreads();
  // ---- build sort keys: (score_bits<<32) | (inv_eid<<14) | k  (score desc, eid asc) ----
#pragma unroll
  for (int j=0;j<NEPT;j++){
    if (em & (1u<<j)){
      int k = t + j*1024;
      float sc = exv[j]/fmaxf(den[dL[j]],1e-16f) + 0.1f;
      u64 inv = (u64)(0x3FFFFu - (unsigned)beid[base+k]);
      skL[k] = ((u64)__float_as_uint(sc) << 32) | (inv << 14) | (u64)k;
    }
  }

  // ---- bitonic sort, descending, NSORT elements ----
  for (unsigned ksz=2; ksz<=NSORT; ksz<<=1){
    for (unsigned jsz=ksz>>1; jsz>0; jsz>>=1){
      __syncthreads();
#pragma unroll 1
      for (int i=t; i<NSORT; i+=1024){
        int jj = i ^ (int)jsz;
        if (jj > i){
          bool up = ((i & (int)ksz) == 0);
          u64 x = skL[i], y = skL[jj];
          if (up ? (x < y) : (x > y)){ skL[i]=y; skL[jj]=x; }
        }
      }
    }
  }
  __syncthreads();

  // ---- compact: rec = (sb<<32)|(s<<23)|(d<<14); same index, no cross-thread hazard ----
#pragma unroll
  for (int q=0;q<NSORT/1024;q++){
    int i = t + q*1024;
    u64 key = skL[i];
    if (key){
      int k_ = (int)(key & 0x3FFFu);
      u64 sv = key >> 32;
      u64 s_ = (u64)(bsrc[base+k_]&511), d_ = (u64)(bdst[base+k_]&511);
      skL[i] = (sv<<32) | (s_<<23) | (d_<<14);
    }
  }
  __syncthreads();

  // ---- single ordered greedy scan (wave 0 only; exact sequential semantics) ----
  if (t < 64){
    int lane = t;
    for (int c0=0; c0<NSORT; c0+=64){
      u64 rec = skL[c0 + lane];
      unsigned long long anyb = __ballot(rec != 0ull);
      if (anyb == 0ull) break;                 // sorted: all-zero tail
      int s = (int)((rec>>23)&511), d = (int)((rec>>14)&511);
      unsigned sb = (unsigned)(rec>>32);
      bool live = (rec!=0ull) && !marked[s] && !marked[d];
      unsigned long long pend = __ballot(live);
      while (pend){
        int first = __builtin_ctzll(pend);
        int sf = __shfl(s, first), df = __shfl(d, first);
        if (lane == first){
          if (s == d){
            marked[s] = 1;
            nscore[(g<<9)+s] = __uint_as_float(sb);
          } else {
            int rep = min(s,d), oth = max(s,d);
            clus[oth] = (unsigned short)rep;
            nscore[(g<<9)+rep] = __uint_as_float(sb);
            valid[(g<<9)+oth] = 0;
            partner[(g<<9)+rep] = (g<<9)+oth;
            marked[s] = 1; marked[d] = 1;
          }
        }
        pend &= ~(1ull<<first);
        bool die = (s==sf || s==df || d==sf || d==df);
        pend &= ~__ballot(die);
      }
    }
  }
  __syncthreads();

  // ---- remap + dedupe (graph-local key table in global scratch) ----
#pragma unroll
  for (int j=0;j<NEPT;j++){
    if (em & (1u<<j)){
      int k = t + j*1024;
      int ns = clus[sL[j]], nd = clus[dL[j]];
      sL[j]=ns; dL[j]=nd;
      bsrc[base+k] = (g<<9)+ns; bdst[base+k] = (g<<9)+nd;
      table[(g<<18) | (ns<<9) | nd] = 0x7FFFFFFF;
    }
  }
  __syncthreads();
#pragma unroll
  for (int j=0;j<NEPT;j++){
    if (em & (1u<<j)){
      int k = t + j*1024;
      atomicMin(&table[(g<<18) | (sL[j]<<9) | dL[j]], base+k);
    }
  }
  __syncthreads();
#pragma unroll
  for (int j=0;j<NEPT;j++){
    if (em & (1u<<j)){
      int k = t + j*1024;
      if (table[(g<<18) | (sL[j]<<9) | dL[j]] != base+k) bem[base+k] = 0;
    }
  }
}

// ---------- pool: new_x = relu((y[i]+y[partner]) * score * valid), pad-zeroed ----------
template<int FO, int FOP>
__global__ __launch_bounds__(256) void k_newx(const float* __restrict__ y, const int* __restrict__ partner,
    const float* __restrict__ nscore, const int* __restrict__ valid, float* __restrict__ out){
  constexpr int Q = (FOP+63)/64;
  int lane = threadIdx.x & 63;
  int nblk = (blockIdx.x & 7)*512 + (blockIdx.x >> 3);
  int i = nblk*4 + (threadIdx.x>>6);
  int v = valid[i];
  float ns = nscore[i];
  int p = partner[i];
  const float* yi = y + (size_t)i*FO;
  const float* yp = (p>=0) ? (y + (size_t)p*FO) : yi;
  float* oi = out + (size_t)i*FOP;
#pragma unroll
  for (int q=0;q<Q;q++){
    int c = lane + q*64;
    if (c<FO){
      float val = yi[c];
      if (p>=0) val += yp[c];
      val *= ns;
      oi[c] = v ? fmaxf(val,0.f) : 0.f;
    } else if (c<FOP){
      oi[c] = 0.f;
    }
  }
}

// ---------- readout: stage 1, per-(graph, 64-row part) partial max ----------
__global__ __launch_bounds__(256) void k_gmax(const float* __restrict__ x, const int* __restrict__ valid,
                                              float* __restrict__ part){
  int g = blockIdx.x >> 3, rp = blockIdx.x & 7;
  __shared__ int lv[64];
  int r0 = rp*64;
  if (threadIdx.x < 64) lv[threadIdx.x] = valid[g*PERG + r0 + threadIdx.x];
  __syncthreads();
  const float* base = x + ((size_t)g*PERG + r0)*600;
  for (int c=threadIdx.x; c<600; c+=256){
    float m = -1e30f;
    for (int r=0;r<64;r++)
      if (lv[r]) m = fmaxf(m, base[(size_t)r*600+c]);
    part[(size_t)(g*8+rp)*600 + c] = m;
  }
}
__global__ __launch_bounds__(256) void k_head(const float* __restrict__ part,
    const float* __restrict__ L1w, const float* __restrict__ L1b,
    const float* __restrict__ L2w, const float* __restrict__ L2b,
    const float* __restrict__ L3w, const float* __restrict__ L3b, float* __restrict__ out){
  int g = blockIdx.x, t = threadIdx.x;
  __shared__ float gg[600];
  __shared__ float z1[200];
  __shared__ float z2[20];
  __shared__ float z3[4];
  for (int c=t;c<600;c+=256){
    float m = -1e30f;
#pragma unroll
    for (int rp=0;rp<8;rp++) m = fmaxf(m, part[(size_t)(g*8+rp)*600 + c]);
    gg[c] = m;
  }
  __syncthreads();
  if (t<200){
    float s = L1b[t];
#pragma unroll 4
    for (int k=0;k<600;k++) s += gg[k]*L1w[k*200+t];
    z1[t] = fmaxf(s,0.f);
  }
  __syncthreads();
  if (t<20){
    float s = L2b[t];
#pragma unroll 4
    for (int k=0;k<200;k++) s += z1[k]*L2w[k*20+t];
    z2[t] = fmaxf(s,0.f);
  }
  __syncthreads();
  if (t<4){
    float s = L3b[t];
    for (int k=0;k<20;k++) s += z2[k]*L3w[k*4+t];
    z3[t] = fmaxf(s,0.f);
  }
  __syncthreads();
  if (t==0){
    float m = fmaxf(fmaxf(z3[0],z3[1]), fmaxf(z3[2],z3[3]));
    float e0=expf(z3[0]-m), e1=expf(z3[1]-m), e2=expf(z3[2]-m), e3=expf(z3[3]-m);
    float s = e0+e1+e2+e3;
    out[g*4+0]=e0/s; out[g*4+1]=e1/s; out[g*4+2]=e2/s; out[g*4+3]=e3/s;
  }
}

// ---------- host orchestration ----------
struct WsPtrs {
  float *A, *B, *x0p, *W1p, *W2p;
  int *bsrc, *bdst, *bem, *beid;
  int *elist, *row_s, *row_e;
  float *dinv, *selfco, *aval, *bval;
  float *nscore; int *partner; int *valid;
  int *gcount;
  float *gbuf;
};

extern "C" void kernel_launch(void* const* d_in, const int* in_sizes, int n_in,
                              void* d_out, int out_size, void* d_ws, size_t ws_size,
                              hipStream_t stream){
  const float* x0  = (const float*)d_in[0];
  const int*   ei  = (const int*)  d_in[1];
  const float* W1  = (const float*)d_in[3];  const float* b1  = (const float*)d_in[4];
  const float* W2  = (const float*)d_in[5];  const float* b2  = (const float*)d_in[6];
  const float* W3  = (const float*)d_in[7];  const float* b3  = (const float*)d_in[8];
  const float* P1w = (const float*)d_in[9];  const float* P1b = (const float*)d_in[10];
  const float* P2w = (const float*)d_in[11]; const float* P2b = (const float*)d_in[12];
  const float* P3w = (const float*)d_in[13]; const float* P3b = (const float*)d_in[14];
  const float* L1w = (const float*)d_in[15]; const float* L1b = (const float*)d_in[16];
  const float* L2w = (const float*)d_in[17]; const float* L2b = (const float*)d_in[18];
  const float* L3w = (const float*)d_in[19]; const float* L3b = (const float*)d_in[20];
  float* out = (float*)d_out;

  char* w = (char*)d_ws;
  size_t off = 0;
  auto alloc = [&](size_t bytes)->void*{
    void* p = w + off;
    off += bytes;
    off = (off + 255) & ~(size_t)255;
    return p;
  };
  WsPtrs P;
  P.A     = (float*)alloc((size_t)NN*600*4);   // ping (also hosts dedupe table when h dead)
  P.B     = (float*)alloc((size_t)NN*600*4);   // pong
  P.x0p   = (float*)alloc((size_t)NN*112*4);
  P.W1p   = (float*)alloc((size_t)112*200*4);
  P.W2p   = (float*)alloc((size_t)208*400*4);
  P.bsrc  = (int*)  alloc((size_t)NGR*GSEG*4);
  P.bdst  = (int*)  alloc((size_t)NGR*GSEG*4);
  P.bem   = (int*)  alloc((size_t)NGR*GSEG*4);
  P.beid  = (int*)  alloc((size_t)NGR*GSEG*4);
  P.elist = (int*)  alloc((size_t)NGR*GSEG*4);
  P.row_s = (int*)  alloc((size_t)NN*4);
  P.row_e = (int*)  alloc((size_t)NN*4);
  P.dinv   = (float*)alloc((size_t)NN*4);
  P.selfco = (float*)alloc((size_t)NN*4);
  P.aval   = (float*)alloc((size_t)NN*4);
  P.bval   = (float*)alloc((size_t)NN*4);
  P.nscore = (float*)alloc((size_t)NN*4);
  P.partner= (int*)  alloc((size_t)NN*4);
  P.valid  = (int*)  alloc((size_t)NN*4);
  P.gcount = (int*)  alloc((size_t)NGR*4);
  P.gbuf   = (float*)alloc((size_t)NGR*8*600*4);
  (void)ws_size; (void)in_sizes; (void)n_in; (void)out_size;

  const int NG4 = NN/4;
  const int POOL_LDS = NSORT * 8;   // 131072 B dynamic LDS (u64 sort array)

  // ---- one-time prep ----
  k_padx<<<(NN*112+255)/256,256,0,stream>>>(x0, P.x0p);
  k_padw<<<(112*200+255)/256,256,0,stream>>>(W1, P.W1p, 107, 112, 200);
  k_padw<<<(208*400+255)/256,256,0,stream>>>(W2, P.W2p, 200, 208, 400);
  hipMemsetAsync(P.gcount, 0, NGR*sizeof(int), stream);
  k_bucket<<<NE/256,256,0,stream>>>(ei, P.gcount, P.bsrc, P.bdst, P.bem, P.beid);
  k_init_nodes<<<NN/256,256,0,stream>>>(P.valid);

  // ---- layer 1: x0p[16384,112] -> h=A(200) -> y=B -> out1=A(stride 208) ----
  { dim3 gmm(4,128); k_mm<<<gmm,256,0,stream>>>(P.x0p, P.W1p, P.A, 112, 200); }
  k_prep<<<NGR,1024,0,stream>>>(P.bsrc,P.bdst,P.bem,P.gcount,P.row_s,P.row_e,P.elist,P.dinv,P.selfco);
  k_aggab<200><<<NG4,256,0,stream>>>(P.A,P.row_s,P.row_e,P.elist,P.dinv,P.selfco,b1,P1w,P.B,P.aval,P.bval);
  k_pool<<<NGR,1024,POOL_LDS,stream>>>(P.gcount,P.bsrc,P.bdst,P.bem,P.beid,
                                P.aval,P.bval,P1b,P.nscore,P.partner,P.valid,(int*)P.A);
  k_newx<200,208><<<NG4,256,0,stream>>>(P.B,P.partner,P.nscore,P.valid,P.A);

  // ---- layer 2: A[16384,208] -> h=B(400) -> y=A -> out2=B(stride 400) ----
  { dim3 gmm(7,128); k_mm<<<gmm,256,0,stream>>>(P.A, P.W2p, P.B, 208, 400); }
  k_prep<<<NGR,1024,0,stream>>>(P.bsrc,P.bdst,P.bem,P.gcount,P.row_s,P.row_e,P.elist,P.dinv,P.selfco);
  k_aggab<400><<<NG4,256,0,stream>>>(P.B,P.row_s,P.row_e,P.elist,P.dinv,P.selfco,b2,P2w,P.A,P.aval,P.bval);
  k_pool<<<NGR,1024,POOL_LDS,stream>>>(P.gcount,P.bsrc,P.bdst,P.bem,P.beid,
                                P.aval,P.bval,P2b,P.nscore,P.partner,P.valid,(int*)P.B);
  k_newx<400,400><<<NG4,256,0,stream>>>(P.A,P.partner,P.nscore,P.valid,P.B);

  // ---- layer 3: B[16384,400] -> h=A(600) -> y=B -> out3=A(stride 600) ----
  { dim3 gmm(10,128); k_mm<<<gmm,256,0,stream>>>(P.B, W3, P.A, 400, 600); }
  k_prep<<<NGR,1024,0,stream>>>(P.bsrc,P.bdst,P.bem,P.gcount,P.row_s,P.row_e,P.elist,P.dinv,P.selfco);
  k_aggab<600><<<NG4,256,0,stream>>>(P.A,P.row_s,P.row_e,P.elist,P.dinv,P.selfco,b3,P3w,P.B,P.aval,P.bval);
  k_pool<<<NGR,1024,POOL_LDS,stream>>>(P.gcount,P.bsrc,P.bdst,P.bem,P.beid,
                                P.aval,P.bval,P3b,P.nscore,P.partner,P.valid,(int*)P.A);
  k_newx<600,600><<<NG4,256,0,stream>>>(P.B,P.partner,P.nscore,P.valid,P.A);

  // ---- readout + MLP head + softmax ----
  k_gmax<<<NGR*8,256,0,stream>>>(P.A, P.valid, P.gbuf);
  k_head<<<NGR,256,0,stream>>>(P.gbuf, L1w, L1b, L2w, L2b, L3w, L3b, out);
}

// Round 11
// 957.945 us; speedup vs baseline: 2.5775x; 1.7568x over previous
//
#include <hip/hip_runtime.h>

#define NN 16384
#define PERG 512
#define NGR 32
#define NE 262144
#define GSEG 9216            // per-graph edge segment capacity (max count ~8.6k)

typedef unsigned long long u64;

// ---------- helpers ----------
__device__ __forceinline__ unsigned encf(float f){
  unsigned u = __float_as_uint(f);
  return (u & 0x80000000u) ? ~u : (u | 0x80000000u);
}
__device__ __forceinline__ float decf(unsigned e){
  unsigned u = (e & 0x80000000u) ? (e ^ 0x80000000u) : ~e;
  return __uint_as_float(u);
}

// ---------- one-time: pad copies for K%16==0 GEMMs ----------
__global__ void k_padx(const float* __restrict__ x, float* __restrict__ xp){
  int i = blockIdx.x*256 + threadIdx.x;          // over NN*112
  if (i < NN*112){ int r = i/112, c = i-r*112; xp[i] = (c<107) ? x[r*107+c] : 0.f; }
}
__global__ void k_padw(const float* __restrict__ Wsrc, float* __restrict__ Wdst,
                       int Ksrc, int Kdst, int N){
  int i = blockIdx.x*256 + threadIdx.x;
  if (i < Kdst*N){ int r = i/N, c = i-r*N; Wdst[i] = (r<Ksrc) ? Wsrc[r*N+c] : 0.f; }
}

// ---------- one-time bucketing: edges -> graph-major segments ----------
__global__ __launch_bounds__(256) void k_bucket(const int* __restrict__ ei, int* __restrict__ gcount,
    int* __restrict__ bsrc, int* __restrict__ bdst, int* __restrict__ bem, int* __restrict__ beid){
  __shared__ int cnt[NGR];
  __shared__ int base[NGR];
  int t = threadIdx.x;
  if (t < NGR) cnt[t] = 0;
  __syncthreads();
  int e = blockIdx.x*256 + t;
  int s=0,d=0,g=0,r=0;
  bool ok = (e < NE);
  if (ok){ s = ei[e]; d = ei[NE+e]; g = s >> 9; r = atomicAdd(&cnt[g],1); }
  __syncthreads();
  if (t < NGR) base[t] = atomicAdd(&gcount[t], cnt[t]);
  __syncthreads();
  if (ok){
    int pos = g*GSEG + base[g] + r;
    bsrc[pos]=s; bdst[pos]=d; bem[pos]=1; beid[pos]=e;
  }
}
__global__ void k_init_nodes(int* __restrict__ valid){
  int i = blockIdx.x*256 + threadIdx.x;
  if (i < NN) valid[i]=1;
}

// ---------- dense matmul C[M,N] = A[M,KP] @ W[KP,N], f32, KP%16==0 ----------
__global__ __launch_bounds__(256) void k_mm(const float* __restrict__ A, const float* __restrict__ W,
                                            float* __restrict__ C, int KP, int N){
  __shared__ float As[16][132];   // A transposed: As[k][row]
  __shared__ float Ws[16][68];
  int col0 = blockIdx.x*64, row0 = blockIdx.y*128;
  int t = threadIdx.x;
  int tx = t & 15, ty = t >> 4;
  int ar = t >> 1;
  int ak = (t & 1) * 8;
  int wk = t >> 4;
  int wn = (t & 15) * 4;
  int wc = col0 + wn;

  float acc[8][4];
#pragma unroll
  for (int i=0;i<8;i++)
#pragma unroll
    for (int j=0;j<4;j++) acc[i][j]=0.f;

  const float* Arow = A + (size_t)(row0+ar)*KP;

  for (int k0=0; k0<KP; k0+=16){
    float4 a0 = *(const float4*)&Arow[k0 + ak];
    float4 a1 = *(const float4*)&Arow[k0 + ak + 4];
    float4 w0;
    const float* wp = &W[(size_t)(k0+wk)*N + wc];
    if (wc+3 < N) w0 = *(const float4*)wp;
    else { w0.x=(wc<N)?wp[0]:0.f; w0.y=(wc+1<N)?wp[1]:0.f; w0.z=(wc+2<N)?wp[2]:0.f; w0.w=0.f; }
    __syncthreads();
    As[ak+0][ar]=a0.x; As[ak+1][ar]=a0.y; As[ak+2][ar]=a0.z; As[ak+3][ar]=a0.w;
    As[ak+4][ar]=a1.x; As[ak+5][ar]=a1.y; As[ak+6][ar]=a1.z; As[ak+7][ar]=a1.w;
    *(float4*)&Ws[wk][wn] = w0;
    __syncthreads();
#pragma unroll
    for (int kk=0;kk<16;kk++){
      float4 A0 = *(const float4*)&As[kk][ty*8];
      float4 A1 = *(const float4*)&As[kk][ty*8+4];
      float4 B0 = *(const float4*)&Ws[kk][tx*4];
      float a[8] = {A0.x,A0.y,A0.z,A0.w,A1.x,A1.y,A1.z,A1.w};
      float b[4] = {B0.x,B0.y,B0.z,B0.w};
#pragma unroll
      for (int i=0;i<8;i++)
#pragma unroll
        for (int j=0;j<4;j++) acc[i][j] += a[i]*b[j];
    }
  }

#pragma unroll
  for (int i=0;i<8;i++){
    int r = row0 + ty*8 + i;
    int cc = col0 + tx*4;
    if (cc+3 < N){
      float4 v = {acc[i][0],acc[i][1],acc[i][2],acc[i][3]};
      *(float4*)&C[(size_t)r*N+cc] = v;
    } else {
#pragma unroll
      for (int j=0;j<4;j++) if (cc+j<N) C[(size_t)r*N+cc+j] = acc[i][j];
    }
  }
}

// ---------- per-graph CSR (by dst) + node prep; elist stores SRC node id ----------
__global__ __launch_bounds__(1024) void k_prep(const int* __restrict__ bsrc, const int* __restrict__ bdst,
    const int* __restrict__ bem, const int* __restrict__ gcount,
    int* __restrict__ row_s, int* __restrict__ row_e, int* __restrict__ elist,
    float* __restrict__ dinv, float* __restrict__ selfco){
  int g = blockIdx.x, t = threadIdx.x;
  __shared__ int cnt_l[PERG];
  __shared__ int scn[PERG];
  __shared__ int cur[PERG];
  __shared__ unsigned char hs_l[PERG];
  if (t<PERG){ cnt_l[t]=0; hs_l[t]=0; }
  __syncthreads();
  int nE = min(gcount[g], GSEG); int base = g*GSEG;
  for (int k=t;k<nE;k+=1024){
    if (bem[base+k]){
      int d = bdst[base+k]&511;
      atomicAdd(&cnt_l[d],1);
      if (bsrc[base+k]==bdst[base+k]) hs_l[d]=1;
    }
  }
  __syncthreads();
  if (t<PERG) scn[t]=cnt_l[t];
  __syncthreads();
  for (int off=1; off<PERG; off<<=1){
    int v = (t<PERG && t>=off) ? scn[t-off] : 0;
    __syncthreads();
    if (t<PERG) scn[t]+=v;
    __syncthreads();
  }
  if (t<PERG){
    int excl = scn[t]-cnt_l[t];
    row_s[g*PERG+t] = base+excl;
    row_e[g*PERG+t] = base+scn[t];
    cur[t] = excl;
    float deg = (float)cnt_l[t] + (hs_l[t]?0.f:1.f);
    dinv[g*PERG+t]   = rsqrtf(deg);
    selfco[g*PERG+t] = hs_l[t]?0.f:(1.f/deg);
  }
  __syncthreads();
  for (int k=t;k<nE;k+=1024){
    if (bem[base+k]){
      int d = bdst[base+k]&511;
      elist[base + atomicAdd(&cur[d],1)] = bsrc[base+k];   // src node id directly
    }
  }
}

// ---------- GCN agg + bias + pool-score partials (fused; XCD-swizzled) ----------
template<int FO>
__global__ __launch_bounds__(256) void k_aggab(const float* __restrict__ h, const int* __restrict__ row_s,
    const int* __restrict__ row_e, const int* __restrict__ elist,
    const float* __restrict__ dinv, const float* __restrict__ selfco, const float* __restrict__ bias,
    const float* __restrict__ Pw, float* __restrict__ y, float* __restrict__ aval, float* __restrict__ bval){
  constexpr int Q = (FO+63)/64;
  int lane = threadIdx.x & 63;
  int nblk = (blockIdx.x & 7)*512 + (blockIdx.x >> 3);
  int i = nblk*4 + (threadIdx.x>>6);
  float acc[Q];
#pragma unroll
  for (int q=0;q<Q;q++) acc[q]=0.f;
  int s0 = row_s[i], s1 = row_e[i];
  float di = dinv[i];
  for (int p=s0; p<s1; p++){
    int s = elist[p];
    float nr = di * dinv[s];
    const float* hrow = h + (size_t)s*FO;
#pragma unroll
    for (int q=0;q<Q;q++){ int c=lane+q*64; if (c<FO) acc[q] += nr*hrow[c]; }
  }
  float sc = selfco[i];
  const float* hi = h + (size_t)i*FO;
  float* yi = y + (size_t)i*FO;
  float sa=0.f, sb=0.f;
#pragma unroll
  for (int q=0;q<Q;q++){
    int c = lane+q*64;
    if (c<FO){
      float v = acc[q] + sc*hi[c] + bias[c];
      yi[c] = v;
      sa += v*Pw[c];
      sb += v*Pw[FO+c];
    }
  }
  for (int o=32;o;o>>=1){ sa += __shfl_xor(sa,o); sb += __shfl_xor(sb,o); }
  if (lane==0){ aval[i]=sa; bval[i]=sb; }
}

// ---------- pool: softmax + compacting local-max matching + remap + dedupe ----------
// rec = (score32<<32) | (inv_eid18<<14) | k14  -> unique; order = (score desc, eid asc)
// matching: atomicMax(best[node], rec); edge commits iff winner at both endpoints;
// live list compacts geometrically each round -> total work ~1.4x one pass.
#define NEPT 9   // 9 * 1024 = 9216 = GSEG
__global__ __launch_bounds__(1024) void k_pool(const int* __restrict__ gcount,
    int* __restrict__ bsrc, int* __restrict__ bdst, int* __restrict__ bem, const int* __restrict__ beid,
    const float* __restrict__ aval, const float* __restrict__ bval, const float* __restrict__ Pb,
    float* __restrict__ nscore, int* __restrict__ partner, int* __restrict__ valid, int* __restrict__ table){
  extern __shared__ u64 dynL[];
  u64* list = dynL;                          // [GSEG]  73.7 KB
  unsigned* sdL = (unsigned*)(dynL + GSEG);  // [GSEG]  36.9 KB
  __shared__ unsigned mx[PERG];
  __shared__ float den[PERG];
  __shared__ u64 best[PERG];
  __shared__ unsigned char marked[PERG];
  __shared__ unsigned short clus[PERG];
  __shared__ int cntA;
  int g = blockIdx.x, t = threadIdx.x;
  int nE = min(gcount[g], GSEG), base = g*GSEG;
  if (t<PERG){
    mx[t]=0u; den[t]=0.f; best[t]=0ull;
    marked[t] = valid[(g<<9)+t] ? 0 : 1;
    clus[t] = (unsigned short)t;
    nscore[(g<<9)+t] = 1.f;
    partner[(g<<9)+t] = -1;
  }
  if (t==0) cntA = 0;
  __syncthreads();

  // ---- softmax over edges grouped by dst ----
  int sL[NEPT], dL[NEPT];
  float rawv[NEPT];
  unsigned em = 0u;
#pragma unroll
  for (int j=0;j<NEPT;j++){
    sL[j]=0; dL[j]=0; rawv[j]=0.f;
    int k = t + j*1024;
    if (k < nE && bem[base+k]){
      sL[j] = bsrc[base+k]&511; dL[j] = bdst[base+k]&511;
      rawv[j] = aval[(g<<9)+sL[j]] + bval[(g<<9)+dL[j]] + Pb[0];
      em |= (1u<<j);
      atomicMax(&mx[dL[j]], encf(rawv[j]));
    }
  }
  __syncthreads();
  float exv[NEPT];
#pragma unroll
  for (int j=0;j<NEPT;j++){
    exv[j]=0.f;
    if (em & (1u<<j)){
      exv[j] = expf(rawv[j] - decf(mx[dL[j]]));
      atomicAdd(&den[dL[j]], exv[j]);
    }
  }
  __syncthreads();
  // ---- build live list + endpoint table ----
#pragma unroll
  for (int j=0;j<NEPT;j++){
    if (em & (1u<<j)){
      int k = t + j*1024;
      float sc = exv[j]/fmaxf(den[dL[j]],1e-16f) + 0.1f;
      int s = sL[j], d = dL[j];
      sdL[k] = ((unsigned)s<<9) | (unsigned)d;
      if (!(marked[s]|marked[d])){
        u64 rec = ((u64)__float_as_uint(sc) << 32)
                | ((u64)(0x3FFFFu - (unsigned)beid[base+k]) << 14) | (u64)k;
        list[atomicAdd(&cntA,1)] = rec;
      }
    }
  }
  __syncthreads();

  // ---- matching: local-max fixed point with live-list compaction ----
  while (true){
    int cn = cntA;
    if (cn == 0) break;
    // pass1: winner per node
    for (int i=t;i<cn;i+=1024){
      u64 rec = list[i];
      unsigned sd = sdL[(unsigned)(rec & 0x3FFFu)];
      int s = sd>>9, d = sd&511;
      atomicMax(&best[s], rec);
      if (d != s) atomicMax(&best[d], rec);
    }
    __syncthreads();
    // pass2: commit mutual winners (unique recs -> no write conflicts)
    for (int i=t;i<cn;i+=1024){
      u64 rec = list[i];
      unsigned sd = sdL[(unsigned)(rec & 0x3FFFu)];
      int s = sd>>9, d = sd&511;
      if (best[s]==rec && (s==d || best[d]==rec)){
        unsigned sb = (unsigned)(rec >> 32);
        if (s == d){
          marked[s] = 1;
          nscore[(g<<9)+s] = __uint_as_float(sb);
        } else {
          int rep = min(s,d), oth = max(s,d);
          clus[oth] = (unsigned short)rep;
          nscore[(g<<9)+rep] = __uint_as_float(sb);
          valid[(g<<9)+oth] = 0;
          partner[(g<<9)+rep] = (g<<9)+oth;
          marked[s] = 1; marked[d] = 1;
        }
      }
    }
    __syncthreads();
    // pass3: gather survivors to registers (fixed slots), compact in place
    u64 keep[NEPT]; unsigned km = 0u;
#pragma unroll
    for (int j=0;j<NEPT;j++){
      keep[j] = 0ull;
      int i = t + j*1024;
      if (i < cn){
        u64 rec = list[i];
        unsigned sd = sdL[(unsigned)(rec & 0x3FFFu)];
        int s = sd>>9, d = sd&511;
        if (!(marked[s]|marked[d])){ keep[j]=rec; km |= (1u<<j); }
      }
    }
    __syncthreads();
    if (t==0) cntA = 0;
    if (t<PERG) best[t] = 0ull;
    __syncthreads();
#pragma unroll
    for (int j=0;j<NEPT;j++){
      if (km & (1u<<j)) list[atomicAdd(&cntA,1)] = keep[j];
    }
    __syncthreads();
  }
  __syncthreads();

  // ---- remap + dedupe (graph-local key table in global scratch) ----
#pragma unroll
  for (int j=0;j<NEPT;j++){
    if (em & (1u<<j)){
      int k = t + j*1024;
      int ns = clus[sL[j]], nd = clus[dL[j]];
      sL[j]=ns; dL[j]=nd;
      bsrc[base+k] = (g<<9)+ns; bdst[base+k] = (g<<9)+nd;
      table[(g<<18) | (ns<<9) | nd] = 0x7FFFFFFF;
    }
  }
  __syncthreads();
#pragma unroll
  for (int j=0;j<NEPT;j++){
    if (em & (1u<<j)){
      int k = t + j*1024;
      atomicMin(&table[(g<<18) | (sL[j]<<9) | dL[j]], base+k);
    }
  }
  __syncthreads();
#pragma unroll
  for (int j=0;j<NEPT;j++){
    if (em & (1u<<j)){
      int k = t + j*1024;
      if (table[(g<<18) | (sL[j]<<9) | dL[j]] != base+k) bem[base+k] = 0;
    }
  }
}

// ---------- pool: new_x = relu((y[i]+y[partner]) * score * valid), pad-zeroed ----------
template<int FO, int FOP>
__global__ __launch_bounds__(256) void k_newx(const float* __restrict__ y, const int* __restrict__ partner,
    const float* __restrict__ nscore, const int* __restrict__ valid, float* __restrict__ out){
  constexpr int Q = (FOP+63)/64;
  int lane = threadIdx.x & 63;
  int nblk = (blockIdx.x & 7)*512 + (blockIdx.x >> 3);
  int i = nblk*4 + (threadIdx.x>>6);
  int v = valid[i];
  float ns = nscore[i];
  int p = partner[i];
  const float* yi = y + (size_t)i*FO;
  const float* yp = (p>=0) ? (y + (size_t)p*FO) : yi;
  float* oi = out + (size_t)i*FOP;
#pragma unroll
  for (int q=0;q<Q;q++){
    int c = lane + q*64;
    if (c<FO){
      float val = yi[c];
      if (p>=0) val += yp[c];
      val *= ns;
      oi[c] = v ? fmaxf(val,0.f) : 0.f;
    } else if (c<FOP){
      oi[c] = 0.f;
    }
  }
}

// ---------- readout: stage 1, per-(graph, 64-row part) partial max ----------
__global__ __launch_bounds__(256) void k_gmax(const float* __restrict__ x, const int* __restrict__ valid,
                                              float* __restrict__ part){
  int g = blockIdx.x >> 3, rp = blockIdx.x & 7;
  __shared__ int lv[64];
  int r0 = rp*64;
  if (threadIdx.x < 64) lv[threadIdx.x] = valid[g*PERG + r0 + threadIdx.x];
  __syncthreads();
  const float* base = x + ((size_t)g*PERG + r0)*600;
  for (int c=threadIdx.x; c<600; c+=256){
    float m = -1e30f;
    for (int r=0;r<64;r++)
      if (lv[r]) m = fmaxf(m, base[(size_t)r*600+c]);
    part[(size_t)(g*8+rp)*600 + c] = m;
  }
}
__global__ __launch_bounds__(256) void k_head(const float* __restrict__ part,
    const float* __restrict__ L1w, const float* __restrict__ L1b,
    const float* __restrict__ L2w, const float* __restrict__ L2b,
    const float* __restrict__ L3w, const float* __restrict__ L3b, float* __restrict__ out){
  int g = blockIdx.x, t = threadIdx.x;
  __shared__ float gg[600];
  __shared__ float z1[200];
  __shared__ float z2[20];
  __shared__ float z3[4];
  for (int c=t;c<600;c+=256){
    float m = -1e30f;
#pragma unroll
    for (int rp=0;rp<8;rp++) m = fmaxf(m, part[(size_t)(g*8+rp)*600 + c]);
    gg[c] = m;
  }
  __syncthreads();
  if (t<200){
    float s = L1b[t];
#pragma unroll 4
    for (int k=0;k<600;k++) s += gg[k]*L1w[k*200+t];
    z1[t] = fmaxf(s,0.f);
  }
  __syncthreads();
  if (t<20){
    float s = L2b[t];
#pragma unroll 4
    for (int k=0;k<200;k++) s += z1[k]*L2w[k*20+t];
    z2[t] = fmaxf(s,0.f);
  }
  __syncthreads();
  if (t<4){
    float s = L3b[t];
    for (int k=0;k<20;k++) s += z2[k]*L3w[k*4+t];
    z3[t] = fmaxf(s,0.f);
  }
  __syncthreads();
  if (t==0){
    float m = fmaxf(fmaxf(z3[0],z3[1]), fmaxf(z3[2],z3[3]));
    float e0=expf(z3[0]-m), e1=expf(z3[1]-m), e2=expf(z3[2]-m), e3=expf(z3[3]-m);
    float s = e0+e1+e2+e3;
    out[g*4+0]=e0/s; out[g*4+1]=e1/s; out[g*4+2]=e2/s; out[g*4+3]=e3/s;
  }
}

// ---------- host orchestration ----------
struct WsPtrs {
  float *A, *B, *x0p, *W1p, *W2p;
  int *bsrc, *bdst, *bem, *beid;
  int *elist, *row_s, *row_e;
  float *dinv, *selfco, *aval, *bval;
  float *nscore; int *partner; int *valid;
  int *gcount;
  float *gbuf;
};

extern "C" void kernel_launch(void* const* d_in, const int* in_sizes, int n_in,
                              void* d_out, int out_size, void* d_ws, size_t ws_size,
                              hipStream_t stream){
  const float* x0  = (const float*)d_in[0];
  const int*   ei  = (const int*)  d_in[1];
  const float* W1  = (const float*)d_in[3];  const float* b1  = (const float*)d_in[4];
  const float* W2  = (const float*)d_in[5];  const float* b2  = (const float*)d_in[6];
  const float* W3  = (const float*)d_in[7];  const float* b3  = (const float*)d_in[8];
  const float* P1w = (const float*)d_in[9];  const float* P1b = (const float*)d_in[10];
  const float* P2w = (const float*)d_in[11]; const float* P2b = (const float*)d_in[12];
  const float* P3w = (const float*)d_in[13]; const float* P3b = (const float*)d_in[14];
  const float* L1w = (const float*)d_in[15]; const float* L1b = (const float*)d_in[16];
  const float* L2w = (const float*)d_in[17]; const float* L2b = (const float*)d_in[18];
  const float* L3w = (const float*)d_in[19]; const float* L3b = (const float*)d_in[20];
  float* out = (float*)d_out;

  char* w = (char*)d_ws;
  size_t off = 0;
  auto alloc = [&](size_t bytes)->void*{
    void* p = w + off;
    off += bytes;
    off = (off + 255) & ~(size_t)255;
    return p;
  };
  WsPtrs P;
  P.A     = (float*)alloc((size_t)NN*600*4);   // ping (also hosts dedupe table when h dead)
  P.B     = (float*)alloc((size_t)NN*600*4);   // pong
  P.x0p   = (float*)alloc((size_t)NN*112*4);
  P.W1p   = (float*)alloc((size_t)112*200*4);
  P.W2p   = (float*)alloc((size_t)208*400*4);
  P.bsrc  = (int*)  alloc((size_t)NGR*GSEG*4);
  P.bdst  = (int*)  alloc((size_t)NGR*GSEG*4);
  P.bem   = (int*)  alloc((size_t)NGR*GSEG*4);
  P.beid  = (int*)  alloc((size_t)NGR*GSEG*4);
  P.elist = (int*)  alloc((size_t)NGR*GSEG*4);
  P.row_s = (int*)  alloc((size_t)NN*4);
  P.row_e = (int*)  alloc((size_t)NN*4);
  P.dinv   = (float*)alloc((size_t)NN*4);
  P.selfco = (float*)alloc((size_t)NN*4);
  P.aval   = (float*)alloc((size_t)NN*4);
  P.bval   = (float*)alloc((size_t)NN*4);
  P.nscore = (float*)alloc((size_t)NN*4);
  P.partner= (int*)  alloc((size_t)NN*4);
  P.valid  = (int*)  alloc((size_t)NN*4);
  P.gcount = (int*)  alloc((size_t)NGR*4);
  P.gbuf   = (float*)alloc((size_t)NGR*8*600*4);
  (void)ws_size; (void)in_sizes; (void)n_in; (void)out_size;

  const int NG4 = NN/4;
  const int POOL_LDS = GSEG*8 + GSEG*4;   // 110,592 B dynamic LDS (list u64 + sd u32)

  // ---- one-time prep ----
  k_padx<<<(NN*112+255)/256,256,0,stream>>>(x0, P.x0p);
  k_padw<<<(112*200+255)/256,256,0,stream>>>(W1, P.W1p, 107, 112, 200);
  k_padw<<<(208*400+255)/256,256,0,stream>>>(W2, P.W2p, 200, 208, 400);
  hipMemsetAsync(P.gcount, 0, NGR*sizeof(int), stream);
  k_bucket<<<NE/256,256,0,stream>>>(ei, P.gcount, P.bsrc, P.bdst, P.bem, P.beid);
  k_init_nodes<<<NN/256,256,0,stream>>>(P.valid);

  // ---- layer 1: x0p[16384,112] -> h=A(200) -> y=B -> out1=A(stride 208) ----
  { dim3 gmm(4,128); k_mm<<<gmm,256,0,stream>>>(P.x0p, P.W1p, P.A, 112, 200); }
  k_prep<<<NGR,1024,0,stream>>>(P.bsrc,P.bdst,P.bem,P.gcount,P.row_s,P.row_e,P.elist,P.dinv,P.selfco);
  k_aggab<200><<<NG4,256,0,stream>>>(P.A,P.row_s,P.row_e,P.elist,P.dinv,P.selfco,b1,P1w,P.B,P.aval,P.bval);
  k_pool<<<NGR,1024,POOL_LDS,stream>>>(P.gcount,P.bsrc,P.bdst,P.bem,P.beid,
                                P.aval,P.bval,P1b,P.nscore,P.partner,P.valid,(int*)P.A);
  k_newx<200,208><<<NG4,256,0,stream>>>(P.B,P.partner,P.nscore,P.valid,P.A);

  // ---- layer 2: A[16384,208] -> h=B(400) -> y=A -> out2=B(stride 400) ----
  { dim3 gmm(7,128); k_mm<<<gmm,256,0,stream>>>(P.A, P.W2p, P.B, 208, 400); }
  k_prep<<<NGR,1024,0,stream>>>(P.bsrc,P.bdst,P.bem,P.gcount,P.row_s,P.row_e,P.elist,P.dinv,P.selfco);
  k_aggab<400><<<NG4,256,0,stream>>>(P.B,P.row_s,P.row_e,P.elist,P.dinv,P.selfco,b2,P2w,P.A,P.aval,P.bval);
  k_pool<<<NGR,1024,POOL_LDS,stream>>>(P.gcount,P.bsrc,P.bdst,P.bem,P.beid,
                                P.aval,P.bval,P2b,P.nscore,P.partner,P.valid,(int*)P.B);
  k_newx<400,400><<<NG4,256,0,stream>>>(P.A,P.partner,P.nscore,P.valid,P.B);

  // ---- layer 3: B[16384,400] -> h=A(600) -> y=B -> out3=A(stride 600) ----
  { dim3 gmm(10,128); k_mm<<<gmm,256,0,stream>>>(P.B, W3, P.A, 400, 600); }
  k_prep<<<NGR,1024,0,stream>>>(P.bsrc,P.bdst,P.bem,P.gcount,P.row_s,P.row_e,P.elist,P.dinv,P.selfco);
  k_aggab<600><<<NG4,256,0,stream>>>(P.A,P.row_s,P.row_e,P.elist,P.dinv,P.selfco,b3,P3w,P.B,P.aval,P.bval);
  k_pool<<<NGR,1024,POOL_LDS,stream>>>(P.gcount,P.bsrc,P.bdst,P.bem,P.beid,
                                P.aval,P.bval,P3b,P.nscore,P.partner,P.valid,(int*)P.A);
  k_newx<600,600><<<NG4,256,0,stream>>>(P.B,P.partner,P.nscore,P.valid,P.A);

  // ---- readout + MLP head + softmax ----
  k_gmax<<<NGR*8,256,0,stream>>>(P.A, P.valid, P.gbuf);
  k_head<<<NGR,256,0,stream>>>(P.gbuf, L1w, L1b, L2w, L2b, L3w, L3b, out);
}

// Round 12
// 945.110 us; speedup vs baseline: 2.6125x; 1.0136x over previous
//
#include <hip/hip_runtime.h>

#define NN 16384
#define PERG 512
#define NGR 32
#define NE 262144
#define GSEG 9216            // per-graph edge segment capacity (max count ~8.6k)
#define HSIZE 16384          // LDS hash slots for dedupe (load factor <= 0.56)

typedef unsigned long long u64;

// ---------- one-time: pad copies for K%16==0 GEMMs ----------
__global__ void k_padx(const float* __restrict__ x, float* __restrict__ xp){
  int i = blockIdx.x*256 + threadIdx.x;          // over NN*112
  if (i < NN*112){ int r = i/112, c = i-r*112; xp[i] = (c<107) ? x[r*107+c] : 0.f; }
}
__global__ void k_padw(const float* __restrict__ Wsrc, float* __restrict__ Wdst,
                       int Ksrc, int Kdst, int N){
  int i = blockIdx.x*256 + threadIdx.x;
  if (i < Kdst*N){ int r = i/N, c = i-r*N; Wdst[i] = (r<Ksrc) ? Wsrc[r*N+c] : 0.f; }
}

// ---------- one-time bucketing: edges -> graph-major segments ----------
__global__ __launch_bounds__(256) void k_bucket(const int* __restrict__ ei, int* __restrict__ gcount,
    int* __restrict__ bsrc, int* __restrict__ bdst, int* __restrict__ bem, int* __restrict__ beid){
  __shared__ int cnt[NGR];
  __shared__ int base[NGR];
  int t = threadIdx.x;
  if (t < NGR) cnt[t] = 0;
  __syncthreads();
  int e = blockIdx.x*256 + t;
  int s=0,d=0,g=0,r=0;
  bool ok = (e < NE);
  if (ok){ s = ei[e]; d = ei[NE+e]; g = s >> 9; r = atomicAdd(&cnt[g],1); }
  __syncthreads();
  if (t < NGR) base[t] = atomicAdd(&gcount[t], cnt[t]);
  __syncthreads();
  if (ok){
    int pos = g*GSEG + base[g] + r;
    bsrc[pos]=s; bdst[pos]=d; bem[pos]=1; beid[pos]=e;
  }
}
__global__ void k_init_nodes(int* __restrict__ valid){
  int i = blockIdx.x*256 + threadIdx.x;
  if (i < NN) valid[i]=1;
}

// ---------- dense matmul C[M,N] = A[M,KP] @ W[KP,N], f32, KP%16==0 ----------
__global__ __launch_bounds__(256) void k_mm(const float* __restrict__ A, const float* __restrict__ W,
                                            float* __restrict__ C, int KP, int N){
  __shared__ float As[16][132];   // A transposed: As[k][row]
  __shared__ float Ws[16][68];
  int col0 = blockIdx.x*64, row0 = blockIdx.y*128;
  int t = threadIdx.x;
  int tx = t & 15, ty = t >> 4;
  int ar = t >> 1;
  int ak = (t & 1) * 8;
  int wk = t >> 4;
  int wn = (t & 15) * 4;
  int wc = col0 + wn;

  float acc[8][4];
#pragma unroll
  for (int i=0;i<8;i++)
#pragma unroll
    for (int j=0;j<4;j++) acc[i][j]=0.f;

  const float* Arow = A + (size_t)(row0+ar)*KP;

  for (int k0=0; k0<KP; k0+=16){
    float4 a0 = *(const float4*)&Arow[k0 + ak];
    float4 a1 = *(const float4*)&Arow[k0 + ak + 4];
    float4 w0;
    const float* wp = &W[(size_t)(k0+wk)*N + wc];
    if (wc+3 < N) w0 = *(const float4*)wp;
    else { w0.x=(wc<N)?wp[0]:0.f; w0.y=(wc+1<N)?wp[1]:0.f; w0.z=(wc+2<N)?wp[2]:0.f; w0.w=0.f; }
    __syncthreads();
    As[ak+0][ar]=a0.x; As[ak+1][ar]=a0.y; As[ak+2][ar]=a0.z; As[ak+3][ar]=a0.w;
    As[ak+4][ar]=a1.x; As[ak+5][ar]=a1.y; As[ak+6][ar]=a1.z; As[ak+7][ar]=a1.w;
    *(float4*)&Ws[wk][wn] = w0;
    __syncthreads();
#pragma unroll
    for (int kk=0;kk<16;kk++){
      float4 A0 = *(const float4*)&As[kk][ty*8];
      float4 A1 = *(const float4*)&As[kk][ty*8+4];
      float4 B0 = *(const float4*)&Ws[kk][tx*4];
      float a[8] = {A0.x,A0.y,A0.z,A0.w,A1.x,A1.y,A1.z,A1.w};
      float b[4] = {B0.x,B0.y,B0.z,B0.w};
#pragma unroll
      for (int i=0;i<8;i++)
#pragma unroll
        for (int j=0;j<4;j++) acc[i][j] += a[i]*b[j];
    }
  }

#pragma unroll
  for (int i=0;i<8;i++){
    int r = row0 + ty*8 + i;
    int cc = col0 + tx*4;
    if (cc+3 < N){
      float4 v = {acc[i][0],acc[i][1],acc[i][2],acc[i][3]};
      *(float4*)&C[(size_t)r*N+cc] = v;
    } else {
#pragma unroll
      for (int j=0;j<4;j++) if (cc+j<N) C[(size_t)r*N+cc+j] = acc[i][j];
    }
  }
}

// ---------- per-graph CSR (by dst) + node prep; elist stores SRC node id ----------
__global__ __launch_bounds__(1024) void k_prep(const int* __restrict__ bsrc, const int* __restrict__ bdst,
    const int* __restrict__ bem, const int* __restrict__ gcount,
    int* __restrict__ row_s, int* __restrict__ row_e, int* __restrict__ elist,
    float* __restrict__ dinv, float* __restrict__ selfco){
  int g = blockIdx.x, t = threadIdx.x;
  __shared__ int cnt_l[PERG];
  __shared__ int scn[PERG];
  __shared__ int cur[PERG];
  __shared__ unsigned char hs_l[PERG];
  if (t<PERG){ cnt_l[t]=0; hs_l[t]=0; }
  __syncthreads();
  int nE = min(gcount[g], GSEG); int base = g*GSEG;
  for (int k=t;k<nE;k+=1024){
    if (bem[base+k]){
      int d = bdst[base+k]&511;
      atomicAdd(&cnt_l[d],1);
      if (bsrc[base+k]==bdst[base+k]) hs_l[d]=1;
    }
  }
  __syncthreads();
  if (t<PERG) scn[t]=cnt_l[t];
  __syncthreads();
  for (int off=1; off<PERG; off<<=1){
    int v = (t<PERG && t>=off) ? scn[t-off] : 0;
    __syncthreads();
    if (t<PERG) scn[t]+=v;
    __syncthreads();
  }
  if (t<PERG){
    int excl = scn[t]-cnt_l[t];
    row_s[g*PERG+t] = base+excl;
    row_e[g*PERG+t] = base+scn[t];
    cur[t] = excl;
    float deg = (float)cnt_l[t] + (hs_l[t]?0.f:1.f);
    dinv[g*PERG+t]   = rsqrtf(deg);
    selfco[g*PERG+t] = hs_l[t]?0.f:(1.f/deg);
  }
  __syncthreads();
  for (int k=t;k<nE;k+=1024){
    if (bem[base+k]){
      int d = bdst[base+k]&511;
      elist[base + atomicAdd(&cur[d],1)] = bsrc[base+k];   // src node id directly
    }
  }
}

// ---------- GCN agg + bias + pool-score partials (fused; XCD-swizzled) ----------
template<int FO>
__global__ __launch_bounds__(256) void k_aggab(const float* __restrict__ h, const int* __restrict__ row_s,
    const int* __restrict__ row_e, const int* __restrict__ elist,
    const float* __restrict__ dinv, const float* __restrict__ selfco, const float* __restrict__ bias,
    const float* __restrict__ Pw, float* __restrict__ y, float* __restrict__ aval, float* __restrict__ bval){
  constexpr int Q = (FO+63)/64;
  int lane = threadIdx.x & 63;
  int nblk = (blockIdx.x & 7)*512 + (blockIdx.x >> 3);
  int i = nblk*4 + (threadIdx.x>>6);
  float acc[Q];
#pragma unroll
  for (int q=0;q<Q;q++) acc[q]=0.f;
  int s0 = row_s[i], s1 = row_e[i];
  float di = dinv[i];
  for (int p=s0; p<s1; p++){
    int s = elist[p];
    float nr = di * dinv[s];
    const float* hrow = h + (size_t)s*FO;
#pragma unroll
    for (int q=0;q<Q;q++){ int c=lane+q*64; if (c<FO) acc[q] += nr*hrow[c]; }
  }
  float sc = selfco[i];
  const float* hi = h + (size_t)i*FO;
  float* yi = y + (size_t)i*FO;
  float sa=0.f, sb=0.f;
#pragma unroll
  for (int q=0;q<Q;q++){
    int c = lane+q*64;
    if (c<FO){
      float v = acc[q] + sc*hi[c] + bias[c];
      yi[c] = v;
      sa += v*Pw[c];
      sb += v*Pw[FO+c];
    }
  }
  for (int o=32;o;o>>=1){ sa += __shfl_xor(sa,o); sb += __shfl_xor(sb,o); }
  if (lane==0){ aval[i]=sa; bval[i]=sb; }
}

// ---------- pool: CSR softmax + compacting local-max matching + LDS-hash dedupe ----------
// rec = (score32<<32) | (inv_eid18<<14) | k14  -> unique; order = (score desc, eid asc)
#define NEPT 9   // 9 * 1024 = 9216 = GSEG
__global__ __launch_bounds__(1024) void k_pool(const int* __restrict__ gcount,
    int* __restrict__ bsrc, int* __restrict__ bdst, int* __restrict__ bem, const int* __restrict__ beid,
    const int* __restrict__ row_s, const int* __restrict__ row_e, const int* __restrict__ elist,
    const float* __restrict__ aval, const float* __restrict__ bval, const float* __restrict__ Pb,
    float* __restrict__ nscore, int* __restrict__ partner, int* __restrict__ valid){
  extern __shared__ u64 dynL[];
  u64* list = dynL;                          // [GSEG]  73.7 KB (matching phase)
  unsigned* sdL = (unsigned*)(dynL + GSEG);  // [GSEG]  36.9 KB
  unsigned* hashT = (unsigned*)dynL;         // [HSIZE] 64 KB   (dedupe phase, overlays list)
  __shared__ float avalL[PERG], bvalL[PERG], mxL[PERG], denL[PERG];
  __shared__ u64 best[PERG];
  __shared__ unsigned char marked[PERG];
  __shared__ unsigned short clus[PERG];
  __shared__ int cntA;
  int g = blockIdx.x, t = threadIdx.x;
  int lane = t & 63;
  int nE = min(gcount[g], GSEG), base = g*GSEG;
  if (t<PERG){
    avalL[t] = aval[(g<<9)+t];
    bvalL[t] = bval[(g<<9)+t];
    best[t]=0ull;
    marked[t] = valid[(g<<9)+t] ? 0 : 1;
    clus[t] = (unsigned short)t;
    nscore[(g<<9)+t] = 1.f;
    partner[(g<<9)+t] = -1;
  }
  if (t==0) cntA = 0;
  __syncthreads();

  // ---- softmax stats per dst node via CSR (no atomics) ----
  float pb = Pb[0];
  if (t<PERG){
    int p0 = row_s[(g<<9)+t], p1 = row_e[(g<<9)+t];
    float bv = bvalL[t];
    float m = -1e30f;
    for (int p=p0;p<p1;p++) m = fmaxf(m, avalL[elist[p]&511] + bv + pb);
    float dn = 0.f;
    for (int p=p0;p<p1;p++) dn += expf(avalL[elist[p]&511] + bv + pb - m);
    mxL[t] = m;
    denL[t] = fmaxf(dn, 1e-16f);
  }
  __syncthreads();

  // ---- per-edge: score + live-list build (wave-aggregated append) ----
  int sL[NEPT], dL[NEPT];
  unsigned em = 0u;
#pragma unroll
  for (int j=0;j<NEPT;j++){
    sL[j]=0; dL[j]=0;
    int k = t + j*1024;
    bool want = false; u64 rec = 0ull;
    if (k < nE && bem[base+k]){
      int s = bsrc[base+k]&511, d = bdst[base+k]&511;
      sL[j]=s; dL[j]=d; em |= (1u<<j);
      sdL[k] = ((unsigned)s<<9) | (unsigned)d;
      if (!(marked[s]|marked[d])){
        float raw = avalL[s] + bvalL[d] + pb;
        float sc = expf(raw - mxL[d]) / denL[d] + 0.1f;
        rec = ((u64)__float_as_uint(sc) << 32)
            | ((u64)(0x3FFFFu - (unsigned)beid[base+k]) << 14) | (u64)k;
        want = true;
      }
    }
    unsigned long long mask = __ballot(want);
    if (want){
      int leader = __builtin_ctzll(mask);
      int rank = __popcll(mask & ((1ull<<lane)-1ull));
      int bs = 0;
      if (lane == leader) bs = atomicAdd(&cntA, __popcll(mask));
      bs = __shfl(bs, leader);
      list[bs + rank] = rec;
    }
  }
  __syncthreads();

  // ---- matching: local-max fixed point with live-list compaction ----
  while (true){
    int cn = cntA;
    if (cn == 0) break;
    for (int i=t;i<cn;i+=1024){
      u64 rec = list[i];
      unsigned sd = sdL[(unsigned)(rec & 0x3FFFu)];
      int s = sd>>9, d = sd&511;
      atomicMax(&best[s], rec);
      if (d != s) atomicMax(&best[d], rec);
    }
    __syncthreads();
    for (int i=t;i<cn;i+=1024){
      u64 rec = list[i];
      unsigned sd = sdL[(unsigned)(rec & 0x3FFFu)];
      int s = sd>>9, d = sd&511;
      if (best[s]==rec && (s==d || best[d]==rec)){
        unsigned sb = (unsigned)(rec >> 32);
        if (s == d){
          marked[s] = 1;
          nscore[(g<<9)+s] = __uint_as_float(sb);
        } else {
          int rep = min(s,d), oth = max(s,d);
          clus[oth] = (unsigned short)rep;
          nscore[(g<<9)+rep] = __uint_as_float(sb);
          valid[(g<<9)+oth] = 0;
          partner[(g<<9)+rep] = (g<<9)+oth;
          marked[s] = 1; marked[d] = 1;
        }
      }
    }
    __syncthreads();
    // gather survivors to fixed register slots, then compact (wave-aggregated)
    u64 keep[NEPT]; unsigned km = 0u;
#pragma unroll
    for (int j=0;j<NEPT;j++){
      keep[j] = 0ull;
      int i = t + j*1024;
      if (i < cn){
        u64 rec = list[i];
        unsigned sd = sdL[(unsigned)(rec & 0x3FFFu)];
        int s = sd>>9, d = sd&511;
        if (!(marked[s]|marked[d])){ keep[j]=rec; km |= (1u<<j); }
      }
    }
    __syncthreads();
    if (t==0) cntA = 0;
    if (t<PERG) best[t] = 0ull;
    __syncthreads();
#pragma unroll
    for (int j=0;j<NEPT;j++){
      bool want = (km & (1u<<j)) != 0u;
      unsigned long long mask = __ballot(want);
      if (want){
        int leader = __builtin_ctzll(mask);
        int rank = __popcll(mask & ((1ull<<lane)-1ull));
        int bs = 0;
        if (lane == leader) bs = atomicAdd(&cntA, __popcll(mask));
        bs = __shfl(bs, leader);
        list[bs + rank] = keep[j];
      }
    }
    __syncthreads();
  }
  __syncthreads();

  // ---- remap + dedupe via LDS hash (overlays dead list area) ----
  for (int i=t;i<HSIZE;i+=1024) hashT[i] = 0xFFFFFFFFu;
  __syncthreads();
#pragma unroll
  for (int j=0;j<NEPT;j++){
    if (em & (1u<<j)){
      int k = t + j*1024;
      int ns = clus[sL[j]], nd = clus[dL[j]];
      sL[j]=ns; dL[j]=nd;
      bsrc[base+k] = (g<<9)+ns; bdst[base+k] = (g<<9)+nd;
      unsigned key = ((unsigned)ns<<9) | (unsigned)nd;          // 18 bits
      unsigned ent = (key<<14) | (unsigned)k;                   // k < 9216 < 2^14
      unsigned hh = (key*2654435761u) >> 18;                    // 14 bits
      for (;;){
        unsigned cur = hashT[hh];
        if (cur == 0xFFFFFFFFu){
          cur = atomicCAS(&hashT[hh], 0xFFFFFFFFu, ent);
          if (cur == 0xFFFFFFFFu) break;        // claimed empty slot
        }
        if ((cur>>14) == key){ atomicMin(&hashT[hh], ent); break; }
        hh = (hh+1) & (HSIZE-1);
      }
    }
  }
  __syncthreads();
#pragma unroll
  for (int j=0;j<NEPT;j++){
    if (em & (1u<<j)){
      int k = t + j*1024;
      unsigned key = ((unsigned)sL[j]<<9) | (unsigned)dL[j];
      unsigned hh = (key*2654435761u) >> 18;
      for (;;){
        unsigned cur = hashT[hh];
        if (cur != 0xFFFFFFFFu && (cur>>14) == key){
          if ((int)(cur & 0x3FFFu) != k) bem[base+k] = 0;
          break;
        }
        hh = (hh+1) & (HSIZE-1);
      }
    }
  }
}

// ---------- pool: new_x = relu((y[i]+y[partner]) * score * valid), pad-zeroed ----------
template<int FO, int FOP>
__global__ __launch_bounds__(256) void k_newx(const float* __restrict__ y, const int* __restrict__ partner,
    const float* __restrict__ nscore, const int* __restrict__ valid, float* __restrict__ out){
  constexpr int Q = (FOP+63)/64;
  int lane = threadIdx.x & 63;
  int nblk = (blockIdx.x & 7)*512 + (blockIdx.x >> 3);
  int i = nblk*4 + (threadIdx.x>>6);
  int v = valid[i];
  float ns = nscore[i];
  int p = partner[i];
  const float* yi = y + (size_t)i*FO;
  const float* yp = (p>=0) ? (y + (size_t)p*FO) : yi;
  float* oi = out + (size_t)i*FOP;
#pragma unroll
  for (int q=0;q<Q;q++){
    int c = lane + q*64;
    if (c<FO){
      float val = yi[c];
      if (p>=0) val += yp[c];
      val *= ns;
      oi[c] = v ? fmaxf(val,0.f) : 0.f;
    } else if (c<FOP){
      oi[c] = 0.f;
    }
  }
}

// ---------- readout: stage 1, per-(graph, 64-row part) partial max ----------
__global__ __launch_bounds__(256) void k_gmax(const float* __restrict__ x, const int* __restrict__ valid,
                                              float* __restrict__ part){
  int g = blockIdx.x >> 3, rp = blockIdx.x & 7;
  __shared__ int lv[64];
  int r0 = rp*64;
  if (threadIdx.x < 64) lv[threadIdx.x] = valid[g*PERG + r0 + threadIdx.x];
  __syncthreads();
  const float* base = x + ((size_t)g*PERG + r0)*600;
  for (int c=threadIdx.x; c<600; c+=256){
    float m = -1e30f;
    for (int r=0;r<64;r++)
      if (lv[r]) m = fmaxf(m, base[(size_t)r*600+c]);
    part[(size_t)(g*8+rp)*600 + c] = m;
  }
}
__global__ __launch_bounds__(256) void k_head(const float* __restrict__ part,
    const float* __restrict__ L1w, const float* __restrict__ L1b,
    const float* __restrict__ L2w, const float* __restrict__ L2b,
    const float* __restrict__ L3w, const float* __restrict__ L3b, float* __restrict__ out){
  int g = blockIdx.x, t = threadIdx.x;
  __shared__ float gg[600];
  __shared__ float z1[200];
  __shared__ float z2[20];
  __shared__ float z3[4];
  for (int c=t;c<600;c+=256){
    float m = -1e30f;
#pragma unroll
    for (int rp=0;rp<8;rp++) m = fmaxf(m, part[(size_t)(g*8+rp)*600 + c]);
    gg[c] = m;
  }
  __syncthreads();
  if (t<200){
    float s = L1b[t];
#pragma unroll 4
    for (int k=0;k<600;k++) s += gg[k]*L1w[k*200+t];
    z1[t] = fmaxf(s,0.f);
  }
  __syncthreads();
  if (t<20){
    float s = L2b[t];
#pragma unroll 4
    for (int k=0;k<200;k++) s += z1[k]*L2w[k*20+t];
    z2[t] = fmaxf(s,0.f);
  }
  __syncthreads();
  if (t<4){
    float s = L3b[t];
    for (int k=0;k<20;k++) s += z2[k]*L3w[k*4+t];
    z3[t] = fmaxf(s,0.f);
  }
  __syncthreads();
  if (t==0){
    float m = fmaxf(fmaxf(z3[0],z3[1]), fmaxf(z3[2],z3[3]));
    float e0=expf(z3[0]-m), e1=expf(z3[1]-m), e2=expf(z3[2]-m), e3=expf(z3[3]-m);
    float s = e0+e1+e2+e3;
    out[g*4+0]=e0/s; out[g*4+1]=e1/s; out[g*4+2]=e2/s; out[g*4+3]=e3/s;
  }
}

// ---------- host orchestration ----------
struct WsPtrs {
  float *A, *B, *x0p, *W1p, *W2p;
  int *bsrc, *bdst, *bem, *beid;
  int *elist, *row_s, *row_e;
  float *dinv, *selfco, *aval, *bval;
  float *nscore; int *partner; int *valid;
  int *gcount;
  float *gbuf;
};

extern "C" void kernel_launch(void* const* d_in, const int* in_sizes, int n_in,
                              void* d_out, int out_size, void* d_ws, size_t ws_size,
                              hipStream_t stream){
  const float* x0  = (const float*)d_in[0];
  const int*   ei  = (const int*)  d_in[1];
  const float* W1  = (const float*)d_in[3];  const float* b1  = (const float*)d_in[4];
  const float* W2  = (const float*)d_in[5];  const float* b2  = (const float*)d_in[6];
  const float* W3  = (const float*)d_in[7];  const float* b3  = (const float*)d_in[8];
  const float* P1w = (const float*)d_in[9];  const float* P1b = (const float*)d_in[10];
  const float* P2w = (const float*)d_in[11]; const float* P2b = (const float*)d_in[12];
  const float* P3w = (const float*)d_in[13]; const float* P3b = (const float*)d_in[14];
  const float* L1w = (const float*)d_in[15]; const float* L1b = (const float*)d_in[16];
  const float* L2w = (const float*)d_in[17]; const float* L2b = (const float*)d_in[18];
  const float* L3w = (const float*)d_in[19]; const float* L3b = (const float*)d_in[20];
  float* out = (float*)d_out;

  char* w = (char*)d_ws;
  size_t off = 0;
  auto alloc = [&](size_t bytes)->void*{
    void* p = w + off;
    off += bytes;
    off = (off + 255) & ~(size_t)255;
    return p;
  };
  WsPtrs P;
  P.A     = (float*)alloc((size_t)NN*600*4);   // ping
  P.B     = (float*)alloc((size_t)NN*600*4);   // pong
  P.x0p   = (float*)alloc((size_t)NN*112*4);
  P.W1p   = (float*)alloc((size_t)112*200*4);
  P.W2p   = (float*)alloc((size_t)208*400*4);
  P.bsrc  = (int*)  alloc((size_t)NGR*GSEG*4);
  P.bdst  = (int*)  alloc((size_t)NGR*GSEG*4);
  P.bem   = (int*)  alloc((size_t)NGR*GSEG*4);
  P.beid  = (int*)  alloc((size_t)NGR*GSEG*4);
  P.elist = (int*)  alloc((size_t)NGR*GSEG*4);
  P.row_s = (int*)  alloc((size_t)NN*4);
  P.row_e = (int*)  alloc((size_t)NN*4);
  P.dinv   = (float*)alloc((size_t)NN*4);
  P.selfco = (float*)alloc((size_t)NN*4);
  P.aval   = (float*)alloc((size_t)NN*4);
  P.bval   = (float*)alloc((size_t)NN*4);
  P.nscore = (float*)alloc((size_t)NN*4);
  P.partner= (int*)  alloc((size_t)NN*4);
  P.valid  = (int*)  alloc((size_t)NN*4);
  P.gcount = (int*)  alloc((size_t)NGR*4);
  P.gbuf   = (float*)alloc((size_t)NGR*8*600*4);
  (void)ws_size; (void)in_sizes; (void)n_in; (void)out_size;

  const int NG4 = NN/4;
  const int POOL_LDS = GSEG*8 + GSEG*4;   // 110,592 B dynamic LDS (list u64 + sd u32; hash overlays)

  // ---- one-time prep ----
  k_padx<<<(NN*112+255)/256,256,0,stream>>>(x0, P.x0p);
  k_padw<<<(112*200+255)/256,256,0,stream>>>(W1, P.W1p, 107, 112, 200);
  k_padw<<<(208*400+255)/256,256,0,stream>>>(W2, P.W2p, 200, 208, 400);
  hipMemsetAsync(P.gcount, 0, NGR*sizeof(int), stream);
  k_bucket<<<NE/256,256,0,stream>>>(ei, P.gcount, P.bsrc, P.bdst, P.bem, P.beid);
  k_init_nodes<<<NN/256,256,0,stream>>>(P.valid);

  // ---- layer 1: x0p[16384,112] -> h=A(200) -> y=B -> out1=A(stride 208) ----
  { dim3 gmm(4,128); k_mm<<<gmm,256,0,stream>>>(P.x0p, P.W1p, P.A, 112, 200); }
  k_prep<<<NGR,1024,0,stream>>>(P.bsrc,P.bdst,P.bem,P.gcount,P.row_s,P.row_e,P.elist,P.dinv,P.selfco);
  k_aggab<200><<<NG4,256,0,stream>>>(P.A,P.row_s,P.row_e,P.elist,P.dinv,P.selfco,b1,P1w,P.B,P.aval,P.bval);
  k_pool<<<NGR,1024,POOL_LDS,stream>>>(P.gcount,P.bsrc,P.bdst,P.bem,P.beid,
                                P.row_s,P.row_e,P.elist,
                                P.aval,P.bval,P1b,P.nscore,P.partner,P.valid);
  k_newx<200,208><<<NG4,256,0,stream>>>(P.B,P.partner,P.nscore,P.valid,P.A);

  // ---- layer 2: A[16384,208] -> h=B(400) -> y=A -> out2=B(stride 400) ----
  { dim3 gmm(7,128); k_mm<<<gmm,256,0,stream>>>(P.A, P.W2p, P.B, 208, 400); }
  k_prep<<<NGR,1024,0,stream>>>(P.bsrc,P.bdst,P.bem,P.gcount,P.row_s,P.row_e,P.elist,P.dinv,P.selfco);
  k_aggab<400><<<NG4,256,0,stream>>>(P.B,P.row_s,P.row_e,P.elist,P.dinv,P.selfco,b2,P2w,P.A,P.aval,P.bval);
  k_pool<<<NGR,1024,POOL_LDS,stream>>>(P.gcount,P.bsrc,P.bdst,P.bem,P.beid,
                                P.row_s,P.row_e,P.elist,
                                P.aval,P.bval,P2b,P.nscore,P.partner,P.valid);
  k_newx<400,400><<<NG4,256,0,stream>>>(P.A,P.partner,P.nscore,P.valid,P.B);

  // ---- layer 3: B[16384,400] -> h=A(600) -> y=B -> out3=A(stride 600) ----
  { dim3 gmm(10,128); k_mm<<<gmm,256,0,stream>>>(P.B, W3, P.A, 400, 600); }
  k_prep<<<NGR,1024,0,stream>>>(P.bsrc,P.bdst,P.bem,P.gcount,P.row_s,P.row_e,P.elist,P.dinv,P.selfco);
  k_aggab<600><<<NG4,256,0,stream>>>(P.A,P.row_s,P.row_e,P.elist,P.dinv,P.selfco,b3,P3w,P.B,P.aval,P.bval);
  k_pool<<<NGR,1024,POOL_LDS,stream>>>(P.gcount,P.bsrc,P.bdst,P.bem,P.beid,
                                P.row_s,P.row_e,P.elist,
                                P.aval,P.bval,P3b,P.nscore,P.partner,P.valid);
  k_newx<600,600><<<NG4,256,0,stream>>>(P.B,P.partner,P.nscore,P.valid,P.A);

  // ---- readout + MLP head + softmax ----
  k_gmax<<<NGR*8,256,0,stream>>>(P.A, P.valid, P.gbuf);
  k_head<<<NGR,256,0,stream>>>(P.gbuf, L1w, L1b, L2w, L2b, L3w, L3b, out);
}